// Round 1
// 480.933 us; speedup vs baseline: 1.0441x; 1.0441x over previous
//
#include <hip/hip_runtime.h>
#include <stdint.h>

#define DEVI __device__ __forceinline__

typedef __bf16 bf16x8 __attribute__((ext_vector_type(8)));
typedef float  f32x4  __attribute__((ext_vector_type(4)));
typedef unsigned int u32x2 __attribute__((ext_vector_type(2)));

// B=4, N=4096, DIM=1024, H=16, D=64, M=128, DIM_INNER=1024, SCALE=0.125

DEVI unsigned short f2bf(float f) {  // RNE f32->bf16
  union { float f; unsigned int u; } c; c.f = f;
  return (unsigned short)((c.u + 0x7fffu + ((c.u >> 16) & 1u)) >> 16);
}
DEVI float bf2f(unsigned short s) {
  union { unsigned int u; float f; } c; c.u = ((unsigned int)s) << 16;
  return c.f;
}
DEVI u32x2 pack4(float a, float b, float c, float d) {
  u32x2 r;
  r.x = (unsigned)f2bf(a) | ((unsigned)f2bf(b) << 16);
  r.y = (unsigned)f2bf(c) | ((unsigned)f2bf(d) << 16);
  return r;
}
DEVI bf16x8 ldg8(const unsigned short* p) { return *(const bf16x8*)p; }

DEVI void g2l16(const void* g, void* l) {
  __builtin_amdgcn_global_load_lds(
      (const __attribute__((address_space(1))) unsigned int*)g,
      (__attribute__((address_space(3))) unsigned int*)l, 16, 0, 0);
}

#define MFMA16(acc, a, b) acc = __builtin_amdgcn_mfma_f32_16x16x32_bf16((a), (b), (acc), 0, 0, 0)

#define VMCNT8() asm volatile("s_waitcnt vmcnt(8)" ::: "memory")
#define VMCNT4() asm volatile("s_waitcnt vmcnt(4)" ::: "memory")
#define VMCNT0() asm volatile("s_waitcnt vmcnt(0)" ::: "memory")
#define SBAR() do { asm volatile("" ::: "memory"); __builtin_amdgcn_s_barrier(); asm volatile("" ::: "memory"); } while (0)

// ---------------- prep: fp32->bf16 cvt + LDS-tiled transposes + rowsum zero -----------
// blocks [0,16384): x | [16384,19456): Wqkv^T | [19456,19584): agent*SCALE
// | [19584,20608): Wout^T | [20608,20616): zero rowsum
__global__ __launch_bounds__(256) void k_prep(
    const float* __restrict__ x, const float* __restrict__ Wqkv,
    const float* __restrict__ ag, const float* __restrict__ Wout,
    unsigned short* __restrict__ Xb, unsigned short* __restrict__ WqkvT,
    unsigned short* __restrict__ Ab, unsigned short* __restrict__ WoT,
    float* __restrict__ rowsum)
{
  __shared__ float ldsT[32][33];
  const int tid = threadIdx.x;
  int bx = blockIdx.x;
  if (bx < 16384) {                     // x: 16.7M elems, 4/thread
    size_t i4 = ((size_t)bx * 256 + tid) * 4;
    f32x4 v = *(const f32x4*)&x[i4];
    *(u32x2*)&Xb[i4] = pack4(v[0], v[1], v[2], v[3]);
    return;
  }
  bx -= 16384;
  if (bx < 3072) {                      // WqkvT[j][k] = Wqkv[k][j], 32x32 tiles
    int jt = bx % 96, kt = bx / 96;
    int r32 = tid >> 3, c4 = (tid & 7) * 4;
    f32x4 v = *(const f32x4*)&Wqkv[(size_t)(kt * 32 + r32) * 3072 + jt * 32 + c4];
#pragma unroll
    for (int i = 0; i < 4; i++) ldsT[r32][c4 + i] = v[i];
    __syncthreads();
    float o0 = ldsT[c4 + 0][r32], o1 = ldsT[c4 + 1][r32];
    float o2 = ldsT[c4 + 2][r32], o3 = ldsT[c4 + 3][r32];
    *(u32x2*)&WqkvT[(size_t)(jt * 32 + r32) * 1024 + kt * 32 + c4] = pack4(o0, o1, o2, o3);
    return;
  }
  bx -= 3072;
  if (bx < 128) {                       // agent tokens * SCALE
    size_t i4 = ((size_t)bx * 256 + tid) * 4;
    f32x4 v = *(const f32x4*)&ag[i4];
    *(u32x2*)&Ab[i4] = pack4(v[0] * 0.125f, v[1] * 0.125f, v[2] * 0.125f, v[3] * 0.125f);
    return;
  }
  bx -= 128;
  if (bx < 1024) {                      // WoT[c][d] = Wout[d][c], 32x32 tiles
    int ct = bx % 32, dt = bx / 32;
    int r32 = tid >> 3, c4 = (tid & 7) * 4;
    f32x4 v = *(const f32x4*)&Wout[(size_t)(dt * 32 + r32) * 1024 + ct * 32 + c4];
#pragma unroll
    for (int i = 0; i < 4; i++) ldsT[r32][c4 + i] = v[i];
    __syncthreads();
    float o0 = ldsT[c4 + 0][r32], o1 = ldsT[c4 + 1][r32];
    float o2 = ldsT[c4 + 2][r32], o3 = ldsT[c4 + 3][r32];
    *(u32x2*)&WoT[(size_t)(ct * 32 + r32) * 1024 + dt * 32 + c4] = pack4(o0, o1, o2, o3);
    return;
  }
  bx -= 1024;
  {                                     // zero rowsum (8 blocks x 1024 floats)
    const f32x4 z = {0.f, 0.f, 0.f, 0.f};
    *(f32x4*)&rowsum[((size_t)bx * 256 + tid) * 4] = z;
  }
}

// =====================================================================================
// 256x256-tile pipelined GEMM core (C = A[M,1024] @ Bt[N,1024]^T), bf16.
// 512 threads = 8 waves (2 Mwave x 4 Nwave); per wave 128x64 out; BK=32.
// LDS = ring of 4 K-tiles (A 16KB + B 16KB each) = 128 KiB -> 1 block/CU.
// Schedule per K-tile: 2 phases x {8/4 ds_read, 2 global_load_lds, barrier,
// setprio(1)+16 MFMA+setprio(0), barrier}; counted vmcnt(8) once per K-tile
// (tiles t+2,t+3 stay in flight across barriers). Ring slot (t+3)&3 was fully
// read in iteration t-1 (lgkm drained before its last barrier), so staging it
// during iteration t is WAR-safe.
// LDS swizzle (T2): 16B-chunk slot = chunk ^ ((row>>1)&3), applied as
// inverse-swizzled GLOBAL source (linear gload_lds dest) + swizzled ds_read.
// swap=1: MFMA A-operand reads the Bt tile (used so Q/K feature dim lands on
// the register-consecutive output-row side).
// =====================================================================================
DEVI void gemm_core_256(const unsigned short* __restrict__ A,
                        const unsigned short* __restrict__ Bt,
                        int row0, int col0, int swap,
                        unsigned short (*lds)[16384], f32x4 acc[8][4])
{
  const int tid = threadIdx.x, lane = tid & 63, w = tid >> 6;
  const int q = lane >> 4, r = lane & 15;
  const int wm = w >> 2, wn = w & 3;
  // ds_read per-lane offset (shorts): row r within frag, swizzled chunk
  const int loff = r * 32 + ((q ^ ((r >> 1) & 3)) << 3);
  // staging: thread covers LDS 16B-slot u = l*512 + tid; row=u>>2, slot=u&3
  const int wslot = w * 512;                              // shorts, wave-uniform LDS base
  const int scol = ((tid & 3) ^ ((tid >> 3) & 3)) << 3;   // inverse-swizzled global chunk
  const int srow = tid >> 2;
  const unsigned short* gA0 = A + (size_t)(row0 + srow) * 1024 + scol;
  const unsigned short* gA1 = gA0 + (size_t)128 * 1024;
  const unsigned short* gB0 = Bt + (size_t)(col0 + srow) * 1024 + scol;
  const unsigned short* gB1 = gB0 + (size_t)128 * 1024;
  const int aoff = (swap ? 8192 : 0) + wm * 4096;
  const int boff = (swap ? 0 : 8192) + wn * 2048;

  const f32x4 z = {0.f, 0.f, 0.f, 0.f};
#pragma unroll
  for (int i = 0; i < 8; i++)
#pragma unroll
    for (int j = 0; j < 4; j++) acc[i][j] = z;

  // prologue: stage K-tiles 0,1,2 into rings 0,1,2 (4 loads each, tile order)
#pragma unroll
  for (int pt = 0; pt < 3; ++pt) {
    unsigned short* lr = &lds[pt][0] + wslot;
    g2l16(gA0 + pt * 32, lr);
    g2l16(gA1 + pt * 32, lr + 4096);
    g2l16(gB0 + pt * 32, lr + 8192);
    g2l16(gB1 + pt * 32, lr + 12288);
  }
  VMCNT8();          // tile 0 landed (tiles 1,2 = newest 8 may fly)
  SBAR();

  for (int t = 0; t < 32; ++t) {
    const unsigned short* rp = &lds[t & 3][0];
    const unsigned short* pA = rp + aoff + loff;
    const unsigned short* pB = rp + boff + loff;
    bf16x8 af[4], bv[4];
    // -------- phase A: frags rt0-3 + all B; stage A-half of tile t+3 --------
#pragma unroll
    for (int rt = 0; rt < 4; rt++) af[rt] = *(const bf16x8*)(pA + rt * 512);
#pragma unroll
    for (int ct = 0; ct < 4; ct++) bv[ct] = *(const bf16x8*)(pB + ct * 512);
    if (t < 29) {
      unsigned short* lr = &lds[(t + 3) & 3][0] + wslot;
      size_t ko = (size_t)(t + 3) * 32;
      g2l16(gA0 + ko, lr);
      g2l16(gA1 + ko, lr + 4096);
    }
    SBAR();
    __builtin_amdgcn_s_setprio(1);
#pragma unroll
    for (int rt = 0; rt < 4; rt++)
#pragma unroll
      for (int ct = 0; ct < 4; ct++) MFMA16(acc[rt][ct], af[rt], bv[ct]);
    __builtin_amdgcn_s_setprio(0);
    SBAR();
    // -------- phase B: frags rt4-7 (bv reused); stage B-half; counted vmcnt --------
#pragma unroll
    for (int rt = 0; rt < 4; rt++) af[rt] = *(const bf16x8*)(pA + (rt + 4) * 512);
    if (t < 29) {
      unsigned short* lr = &lds[(t + 3) & 3][0] + wslot;
      size_t ko = (size_t)(t + 3) * 32;
      g2l16(gB0 + ko, lr + 8192);
      g2l16(gB1 + ko, lr + 12288);
    }
    if (t < 29)      { VMCNT8(); }   // tile t+1 landed; t+2,t+3 in flight
    else if (t == 29) { VMCNT4(); }  // tail drain
    else if (t == 30) { VMCNT0(); }
    SBAR();
    __builtin_amdgcn_s_setprio(1);
#pragma unroll
    for (int rt = 0; rt < 4; rt++)
#pragma unroll
      for (int ct = 0; ct < 4; ct++) MFMA16(acc[rt + 4][ct], af[rt], bv[ct]);
    __builtin_amdgcn_s_setprio(0);
    SBAR();
  }
}

// ---------------- GEMM1: C[16384,3072] = Xb @ WqkvT^T ; scatter to Q,K,Vt -------------
// grid (x=row 64, y=col 12), 256x256 tiles. Q/K col-blocks: swapped roles ->
// D[j,n], d reg-consecutive. V: D[n,j], n reg-consecutive.
__global__ __launch_bounds__(512, 2) void k_gemm_qkv(
    const unsigned short* __restrict__ A, const unsigned short* __restrict__ Bt,
    unsigned short* __restrict__ Q, unsigned short* __restrict__ Kd,
    unsigned short* __restrict__ Vt)
{
  __shared__ __align__(16) unsigned short lds[4][16384];
  const int tid = threadIdx.x, lane = tid & 63, w = tid >> 6;
  const int q = lane >> 4, r = lane & 15, wm = w >> 2, wn = w & 3;
  const int row0 = blockIdx.x * 256, col0 = blockIdx.y * 256;
  const bool qk = blockIdx.y < 8;

  f32x4 acc[8][4];
  gemm_core_256(A, Bt, row0, col0, qk ? 1 : 0, lds, acc);

  const int b = row0 >> 12, row0b = row0 & 4095;
  if (qk) {   // D[row=j_local, col=n_local]
    unsigned short* dst = (col0 < 1024) ? Q : Kd;
    const int jb = (col0 & 1023) + wm * 128;
#pragma unroll
    for (int rt = 0; rt < 8; rt++)
#pragma unroll
      for (int ct = 0; ct < 4; ct++) {
        int j = jb + rt * 16 + 4 * q;
        int h = j >> 6, d0 = j & 63;
        int n = row0b + wn * 64 + ct * 16 + r;
        u32x2 pk = pack4(acc[rt][ct][0], acc[rt][ct][1], acc[rt][ct][2], acc[rt][ct][3]);
        *(u32x2*)&dst[(((size_t)(b * 16 + h)) * 4096 + n) * 64 + d0] = pk;
      }
  } else {    // D[row=n, col=j]; pack 4 consecutive n into Vt[b,h,d,n]
    const int jb = (col0 - 2048) + wn * 64;
#pragma unroll
    for (int rt = 0; rt < 8; rt++)
#pragma unroll
      for (int ct = 0; ct < 4; ct++) {
        int j = jb + ct * 16 + r;
        int h = j >> 6, d = j & 63;
        int n = row0b + wm * 128 + rt * 16 + 4 * q;
        u32x2 pk = pack4(acc[rt][ct][0], acc[rt][ct][1], acc[rt][ct][2], acc[rt][ct][3]);
        *(u32x2*)&Vt[(((size_t)(b * 16 + h)) * 64 + d) * 4096 + n] = pk;
      }
  }
}

// ------- qk: fused qa (softmax over m -> QA[b,h,n,m]) + ak (mask+exp -> E[b,h,m,n]) ---
__global__ __launch_bounds__(256, 2) void k_qk(
    const unsigned short* __restrict__ Q, const unsigned short* __restrict__ Kd,
    const unsigned short* __restrict__ Ab, const int* __restrict__ mask,
    unsigned short* __restrict__ QA, unsigned short* __restrict__ E,
    float* __restrict__ rowsum)
{
  const int tid = threadIdx.x, lane = tid & 63, w = tid >> 6;
  const int q = lane >> 4, r = lane & 15, wr = w >> 1, wc = w & 1;
  const int nt = blockIdx.x, h = blockIdx.y, b = blockIdx.z;
  const unsigned short* Qb = Q + (((size_t)(b * 16 + h)) * 4096 + nt * 128) * 64;
  const unsigned short* Kb = Kd + (((size_t)(b * 16 + h)) * 4096 + nt * 128) * 64;
  const unsigned short* Ah = Ab + (size_t)h * 8192;
  __shared__ float rs[2][128];
  const f32x4 z = {0.f, 0.f, 0.f, 0.f};

  // ================= qa part: D[m,n] (A=agent rows m, B=Q rows n) =================
  {
    f32x4 acc[4][4];
#pragma unroll
    for (int i = 0; i < 4; i++)
#pragma unroll
      for (int j = 0; j < 4; j++) acc[i][j] = z;
#pragma unroll
    for (int ks = 0; ks < 2; ks++) {
      bf16x8 af[4], bv[4];
#pragma unroll
      for (int rt = 0; rt < 4; rt++) af[rt] = ldg8(Ah + (size_t)(64 * wr + 16 * rt + r) * 64 + ks * 32 + q * 8);
#pragma unroll
      for (int ct = 0; ct < 4; ct++) bv[ct] = ldg8(Qb + (size_t)(64 * wc + 16 * ct + r) * 64 + ks * 32 + q * 8);
#pragma unroll
      for (int rt = 0; rt < 4; rt++)
#pragma unroll
        for (int ct = 0; ct < 4; ct++) MFMA16(acc[rt][ct], af[rt], bv[ct]);
    }
    float cs[4];
#pragma unroll
    for (int ct = 0; ct < 4; ct++) {
      float s = 0.f;
#pragma unroll
      for (int rt = 0; rt < 4; rt++)
#pragma unroll
        for (int reg = 0; reg < 4; reg++) {
          float e = __expf(acc[rt][ct][reg]);
          acc[rt][ct][reg] = e; s += e;
        }
      s += __shfl_xor(s, 16); s += __shfl_xor(s, 32);
      cs[ct] = s;
    }
    if (q == 0) {
#pragma unroll
      for (int ct = 0; ct < 4; ct++) rs[wr][64 * wc + 16 * ct + r] = cs[ct];
    }
    __syncthreads();
#pragma unroll
    for (int ct = 0; ct < 4; ct++) {
      int nl = 64 * wc + 16 * ct + r;
      float inv = 1.0f / (rs[0][nl] + rs[1][nl]);
      int n = nt * 128 + nl;
      size_t base = (((size_t)(b * 16 + h)) * 4096 + n) * 128;
#pragma unroll
      for (int rt = 0; rt < 4; rt++) {
        int m0 = 64 * wr + 16 * rt + 4 * q;
        u32x2 pk = pack4(acc[rt][ct][0] * inv, acc[rt][ct][1] * inv,
                         acc[rt][ct][2] * inv, acc[rt][ct][3] * inv);
        *(u32x2*)&QA[base + m0] = pk;
      }
    }
  }
  __syncthreads();   // rs WAR hazard between sections

  // ================= ak part: D[n,m] (A=K rows n, B=agent rows m) =================
  {
    f32x4 acc[4][4];
#pragma unroll
    for (int i = 0; i < 4; i++)
#pragma unroll
      for (int j = 0; j < 4; j++) acc[i][j] = z;
#pragma unroll
    for (int ks = 0; ks < 2; ks++) {
      bf16x8 af[4], bv[4];
#pragma unroll
      for (int rt = 0; rt < 4; rt++) af[rt] = ldg8(Kb + (size_t)(64 * wr + 16 * rt + r) * 64 + ks * 32 + q * 8);
#pragma unroll
      for (int ct = 0; ct < 4; ct++) bv[ct] = ldg8(Ah + (size_t)(64 * wc + 16 * ct + r) * 64 + ks * 32 + q * 8);
#pragma unroll
      for (int rt = 0; rt < 4; rt++)
#pragma unroll
        for (int ct = 0; ct < 4; ct++) MFMA16(acc[rt][ct], af[rt], bv[ct]);
    }
    float cs[4] = {0.f, 0.f, 0.f, 0.f};
#pragma unroll
    for (int rt = 0; rt < 4; rt++) {
      const int4 mkv = *(const int4*)&mask[b * 4096 + nt * 128 + 64 * wr + 16 * rt + 4 * q];
      int mka[4] = {mkv.x, mkv.y, mkv.z, mkv.w};
#pragma unroll
      for (int ct = 0; ct < 4; ct++) {
#pragma unroll
        for (int reg = 0; reg < 4; reg++) {
          float e = mka[reg] ? __expf(acc[rt][ct][reg]) : 0.0f;
          acc[rt][ct][reg] = e; cs[ct] += e;
        }
      }
    }
#pragma unroll
    for (int ct = 0; ct < 4; ct++) {
      float s = cs[ct];
      s += __shfl_xor(s, 16); s += __shfl_xor(s, 32);
      cs[ct] = s;
    }
    if (q == 0) {
#pragma unroll
      for (int ct = 0; ct < 4; ct++) rs[wr][64 * wc + 16 * ct + r] = cs[ct];
    }
#pragma unroll
    for (int ct = 0; ct < 4; ct++) {
      int m = 64 * wc + 16 * ct + r;
      size_t base = (((size_t)(b * 16 + h)) * 128 + m) * 4096;
#pragma unroll
      for (int rt = 0; rt < 4; rt++) {
        int n0 = nt * 128 + 64 * wr + 16 * rt + 4 * q;
        u32x2 pk = pack4(acc[rt][ct][0], acc[rt][ct][1], acc[rt][ct][2], acc[rt][ct][3]);
        *(u32x2*)&E[base + n0] = pk;
      }
    }
    __syncthreads();
    if (tid < 128) atomicAdd(&rowsum[(b * 16 + h) * 128 + tid], rs[0][tid] + rs[1][tid]);
  }
}

// ---- mix: MIX[g,m,n] = sum_h Wak[g,h]*E[h,m,n]/rowsum[h,m]  (4 elems/thread, 8B IO) --
__global__ __launch_bounds__(256) void k_mix(
    const unsigned short* __restrict__ E, const float* __restrict__ rowsum,
    const float* __restrict__ Wak, unsigned short* __restrict__ MIX)
{
  const int tid = threadIdx.x;
  const int m = blockIdx.y, b = blockIdx.z;
  __shared__ float wv[256];
  __shared__ float inv[16];
  wv[tid] = Wak[tid];
  if (tid < 16) inv[tid] = 1.0f / rowsum[(b * 16 + tid) * 128 + m];
  __syncthreads();
  const int n0 = (blockIdx.x * 256 + tid) * 4;
  float p[16][4];
#pragma unroll
  for (int h = 0; h < 16; h++) {
    u32x2 v = *(const u32x2*)&E[(((size_t)(b * 16 + h)) * 128 + m) * 4096 + n0];
    float iv = inv[h];
    p[h][0] = bf2f((unsigned short)(v.x & 0xffff)) * iv;
    p[h][1] = bf2f((unsigned short)(v.x >> 16)) * iv;
    p[h][2] = bf2f((unsigned short)(v.y & 0xffff)) * iv;
    p[h][3] = bf2f((unsigned short)(v.y >> 16)) * iv;
  }
#pragma unroll
  for (int g = 0; g < 16; g++) {
    float s0 = 0.f, s1 = 0.f, s2 = 0.f, s3 = 0.f;
#pragma unroll
    for (int h = 0; h < 16; h++) {
      float wgh = wv[g * 16 + h];
      s0 += wgh * p[h][0]; s1 += wgh * p[h][1]; s2 += wgh * p[h][2]; s3 += wgh * p[h][3];
    }
    *(u32x2*)&MIX[(((size_t)(b * 16 + g)) * 128 + m) * 4096 + n0] = pack4(s0, s1, s2, s3);
  }
}

// ------ k_ao: partial AO_T planes P[kc][b,g,d,m] = MIX[b,g] @ V[b,g] (k-chunk) --------
__global__ __launch_bounds__(256) void k_ao(
    const unsigned short* __restrict__ MIX, const unsigned short* __restrict__ Vt,
    float* __restrict__ P)
{
  const int tid = threadIdx.x, lane = tid & 63, w4 = tid >> 6;
  const int q = lane >> 4, r = lane & 15;
  const int kc = blockIdx.x, g = blockIdx.y, b = blockIdx.z;
  const unsigned short* Abase = MIX + ((size_t)(b * 16 + g)) * 128 * 4096;
  const unsigned short* Bbase = Vt + ((size_t)(b * 16 + g)) * 64 * 4096;
  f32x4 acc[2][4];
  const f32x4 z = {0.f, 0.f, 0.f, 0.f};
#pragma unroll
  for (int i = 0; i < 2; i++)
#pragma unroll
    for (int j = 0; j < 4; j++) acc[i][j] = z;
  for (int n = kc * 512; n < kc * 512 + 512; n += 32) {
    bf16x8 af[2], bv[4];
#pragma unroll
    for (int rt = 0; rt < 2; rt++) af[rt] = ldg8(Abase + (size_t)(32 * w4 + 16 * rt + r) * 4096 + n + q * 8);
#pragma unroll
    for (int ct = 0; ct < 4; ct++) bv[ct] = ldg8(Bbase + (size_t)(16 * ct + r) * 4096 + n + q * 8);
#pragma unroll
    for (int rt = 0; rt < 2; rt++)
#pragma unroll
      for (int ct = 0; ct < 4; ct++) MFMA16(acc[rt][ct], af[rt], bv[ct]);
  }
  float* Pp = P + (size_t)kc * 524288 + ((size_t)(b * 16 + g)) * 8192;
#pragma unroll
  for (int rt = 0; rt < 2; rt++)
#pragma unroll
    for (int ct = 0; ct < 4; ct++) {
      int m0 = 32 * w4 + 16 * rt + 4 * q, d = 16 * ct + r;
      *(f32x4*)&Pp[(size_t)d * 128 + m0] = acc[rt][ct];   // regs = consecutive m
    }
}

// ------ aored: AOt = sum_kc P[kc]  (524288 fp32) --------------------------------------
__global__ __launch_bounds__(256) void k_aored(
    const float* __restrict__ P, float* __restrict__ AOt)
{
  size_t i = ((size_t)blockIdx.x * 256 + threadIdx.x) * 4;
  f32x4 s = *(const f32x4*)&P[i];
#pragma unroll
  for (int kc = 1; kc < 8; kc++) {
    f32x4 v = *(const f32x4*)&P[(size_t)kc * 524288 + i];
    s[0] += v[0]; s[1] += v[1]; s[2] += v[2]; s[3] += v[3];
  }
  *(f32x4*)&AOt[i] = s;
}

// ---- mixqa: QAmix[g,plane] = sum_h Wqa[g,h]*QA[h,plane]  (4 elems/thread, 8B IO) -----
__global__ __launch_bounds__(256) void k_mixqa(
    const unsigned short* __restrict__ QA, const float* __restrict__ Wqa,
    unsigned short* __restrict__ QAmix)
{
  const int tid = threadIdx.x;
  const int b = blockIdx.y;
  __shared__ float wv[256];
  wv[tid] = Wqa[tid];
  __syncthreads();
  const size_t i0 = ((size_t)blockIdx.x * 256 + tid) * 4;   // plane 524288 elems
  float p[16][4];
#pragma unroll
  for (int h = 0; h < 16; h++) {
    u32x2 v = *(const u32x2*)&QA[((size_t)(b * 16 + h)) * 524288 + i0];
    p[h][0] = bf2f((unsigned short)(v.x & 0xffff));
    p[h][1] = bf2f((unsigned short)(v.x >> 16));
    p[h][2] = bf2f((unsigned short)(v.y & 0xffff));
    p[h][3] = bf2f((unsigned short)(v.y >> 16));
  }
#pragma unroll
  for (int g = 0; g < 16; g++) {
    float s0 = 0.f, s1 = 0.f, s2 = 0.f, s3 = 0.f;
#pragma unroll
    for (int h = 0; h < 16; h++) {
      float wgh = wv[g * 16 + h];
      s0 += wgh * p[h][0]; s1 += wgh * p[h][1]; s2 += wgh * p[h][2]; s3 += wgh * p[h][3];
    }
    *(u32x2*)&QAmix[((size_t)(b * 16 + g)) * 524288 + i0] = pack4(s0, s1, s2, s3);
  }
}

// ---- o1: swapped roles -> D[d,n]; out1[b,n,g*64+d] 8B stores; reads AO_T fp32 --------
__global__ __launch_bounds__(256) void k_o1(
    const unsigned short* __restrict__ QAmix, const float* __restrict__ AOt,
    unsigned short* __restrict__ out1)
{
  const int tid = threadIdx.x, lane = tid & 63, w4 = tid >> 6;
  const int q = lane >> 4, r = lane & 15;
  const int nt = blockIdx.x, g = blockIdx.y, b = blockIdx.z;
  const unsigned short* Bbase = QAmix + (((size_t)(b * 16 + g)) * 4096 + nt * 128) * 128;
  const float* Abase = AOt + ((size_t)(b * 16 + g)) * 8192;   // [d][m]
  f32x4 acc[4][2];
  const f32x4 z = {0.f, 0.f, 0.f, 0.f};
#pragma unroll
  for (int i = 0; i < 4; i++)
#pragma unroll
    for (int j = 0; j < 2; j++) acc[i][j] = z;
#pragma unroll
  for (int ks = 0; ks < 4; ks++) {
    bf16x8 af[4], bv[2];
#pragma unroll
    for (int rt = 0; rt < 4; rt++) {
      const float* p = Abase + (size_t)(16 * rt + r) * 128 + ks * 32 + q * 8;
      f32x4 f0 = *(const f32x4*)p;
      f32x4 f1 = *(const f32x4*)(p + 4);
      bf16x8 t;
#pragma unroll
      for (int jj = 0; jj < 4; jj++) { t[jj] = (__bf16)f0[jj]; t[4 + jj] = (__bf16)f1[jj]; }
      af[rt] = t;
    }
#pragma unroll
    for (int ct = 0; ct < 2; ct++)
      bv[ct] = ldg8(Bbase + (size_t)(32 * w4 + 16 * ct + r) * 128 + ks * 32 + q * 8);
#pragma unroll
    for (int rt = 0; rt < 4; rt++)
#pragma unroll
      for (int ct = 0; ct < 2; ct++) MFMA16(acc[rt][ct], af[rt], bv[ct]);
  }
#pragma unroll
  for (int ct = 0; ct < 2; ct++) {
    int n = nt * 128 + 32 * w4 + 16 * ct + r;
    size_t base = ((size_t)b * 4096 + n) * 1024 + g * 64;
#pragma unroll
    for (int rt = 0; rt < 4; rt++) {
      int d0 = 16 * rt + 4 * q;
      u32x2 pk = pack4(acc[rt][ct][0], acc[rt][ct][1], acc[rt][ct][2], acc[rt][ct][3]);
      *(u32x2*)&out1[base + d0] = pk;
    }
  }
}

// ------- fin2: out[16384,1024] = out1 @ WoT^T, mask rows, fp32; 256x256 tiles ---------
__global__ __launch_bounds__(512, 2) void k_fin2(
    const unsigned short* __restrict__ A, const unsigned short* __restrict__ Bt,
    const int* __restrict__ mask, float* __restrict__ out)
{
  __shared__ __align__(16) unsigned short lds[4][16384];
  const int tid = threadIdx.x, lane = tid & 63, w = tid >> 6;
  const int q = lane >> 4, r = lane & 15, wm = w >> 2, wn = w & 3;
  const int row0 = blockIdx.x * 256, col0 = blockIdx.y * 256;

  f32x4 acc[8][4];
  gemm_core_256(A, Bt, row0, col0, 0, lds, acc);

#pragma unroll
  for (int rt = 0; rt < 8; rt++) {
    const int4 mkv = *(const int4*)&mask[row0 + wm * 128 + rt * 16 + 4 * q];
    int mka[4] = {mkv.x, mkv.y, mkv.z, mkv.w};
#pragma unroll
    for (int reg = 0; reg < 4; reg++) {
      int row = row0 + wm * 128 + rt * 16 + 4 * q + reg;
#pragma unroll
      for (int ct = 0; ct < 4; ct++) {
        int c = col0 + wn * 64 + ct * 16 + r;
        out[(size_t)row * 1024 + c] = mka[reg] ? acc[rt][ct][reg] : 0.0f;
      }
    }
  }
}

// =====================================================================================
extern "C" void kernel_launch(void* const* d_in, const int* in_sizes, int n_in,
                              void* d_out, int out_size, void* d_ws, size_t ws_size,
                              hipStream_t stream) {
  const float* x    = (const float*)d_in[0];
  const int*   mask = (const int*)d_in[1];
  const float* Wqkv = (const float*)d_in[2];
  const float* ag   = (const float*)d_in[3];
  const float* Wqa  = (const float*)d_in[4];
  const float* Wak  = (const float*)d_in[5];
  const float* Wout = (const float*)d_in[6];
  float* out = (float*)d_out;
  char* ws = (char*)d_ws;

  // workspace layout, lifetime-overlapped; total 239,370,240 B (unchanged)
  unsigned short* QA    = (unsigned short*)(ws + 0);           // [qk -> mixqa]
  unsigned short* QQ    = (unsigned short*)(ws + 67108864);    // Q [gemm -> qk]
  unsigned short* KK    = (unsigned short*)(ws + 67108864 + 33554432);  // K [gemm -> qk]
  unsigned short* MIX   = QQ;                                  // [mix -> ao] (spans QQ+KK)
  unsigned short* out1  = QQ;                                  // [o1 -> fin2]
  unsigned short* VT    = (unsigned short*)(ws + 134217728);   // Vt [gemm -> ao]
  unsigned short* Xb    = (unsigned short*)(ws + 167772160);   // [prep -> gemm]
  unsigned short* WqkvT = (unsigned short*)(ws + 167772160 + 33554432);
  unsigned short* E     = Xb;                                  // [qk -> mix]
  float*          Ppart = (float*)Xb;                          // 16MB [ao -> aored] (E dead)
  unsigned short* QAmix = Xb;                                  // [mixqa -> o1] (Ppart dead)
  char* sm = ws + 234881024;
  unsigned short* Ab  = (unsigned short*)(sm);                 // 256 KB
  unsigned short* WoT = (unsigned short*)(sm + 262144);        // 2 MB
  float* rowsum = (float*)(sm + 262144 + 2097152);             // 32 KB
  float* AOt    = (float*)(sm + 262144 + 2097152 + 32768);     // 2 MB [b,g,d,m] fp32

  k_prep<<<20616, 256, 0, stream>>>(x, Wqkv, ag, Wout, Xb, WqkvT, Ab, WoT, rowsum);
  k_gemm_qkv<<<dim3(64, 12), 512, 0, stream>>>(Xb, WqkvT, QQ, KK, VT);
  k_qk<<<dim3(32, 16, 4), 256, 0, stream>>>(QQ, KK, Ab, mask, QA, E, rowsum);
  k_mix<<<dim3(4, 128, 4), 256, 0, stream>>>(E, rowsum, Wak, MIX);
  k_ao<<<dim3(8, 16, 4), 256, 0, stream>>>(MIX, VT, Ppart);
  k_aored<<<512, 256, 0, stream>>>(Ppart, AOt);
  k_mixqa<<<dim3(512, 4), 256, 0, stream>>>(QA, Wqa, QAmix);
  k_o1<<<dim3(32, 16, 4), 256, 0, stream>>>(QAmix, AOt, out1);
  k_fin2<<<dim3(64, 4), 512, 0, stream>>>(out1, WoT, mask, out);
}

// Round 2
// 468.036 us; speedup vs baseline: 1.0729x; 1.0276x over previous
//
#include <hip/hip_runtime.h>
#include <stdint.h>

#define DEVI __device__ __forceinline__

typedef __bf16 bf16x8 __attribute__((ext_vector_type(8)));
typedef float  f32x4  __attribute__((ext_vector_type(4)));
typedef unsigned int u32x2 __attribute__((ext_vector_type(2)));

// B=4, N=4096, DIM=1024, H=16, D=64, M=128, DIM_INNER=1024, SCALE=0.125

DEVI unsigned short f2bf(float f) {  // RNE f32->bf16
  union { float f; unsigned int u; } c; c.f = f;
  return (unsigned short)((c.u + 0x7fffu + ((c.u >> 16) & 1u)) >> 16);
}
DEVI float bf2f(unsigned short s) {
  union { unsigned int u; float f; } c; c.u = ((unsigned int)s) << 16;
  return c.f;
}
DEVI u32x2 pack4(float a, float b, float c, float d) {
  u32x2 r;
  r.x = (unsigned)f2bf(a) | ((unsigned)f2bf(b) << 16);
  r.y = (unsigned)f2bf(c) | ((unsigned)f2bf(d) << 16);
  return r;
}
DEVI bf16x8 ldg8(const unsigned short* p) { return *(const bf16x8*)p; }

DEVI void g2l16(const void* g, void* l) {
  __builtin_amdgcn_global_load_lds(
      (const __attribute__((address_space(1))) unsigned int*)g,
      (__attribute__((address_space(3))) unsigned int*)l, 16, 0, 0);
}

#define MFMA16(acc, a, b) acc = __builtin_amdgcn_mfma_f32_16x16x32_bf16((a), (b), (acc), 0, 0, 0)

// Template-faithful sync idiom (m201/HK): BARE waits + BARE s_barrier.
// NO "memory" clobbers — a memory-clobber asm makes the memory legalizer
// insert s_waitcnt vmcnt(0) lgkmcnt(0) before it (defeats the counted-vmcnt
// pipeline; round-1 post-mortem).
#define VMCNT8() asm volatile("s_waitcnt vmcnt(8)")
#define VMCNT4() asm volatile("s_waitcnt vmcnt(4)")
#define VMCNT0() asm volatile("s_waitcnt vmcnt(0)")
#define LGKM0()  asm volatile("s_waitcnt lgkmcnt(0)")
#define SBAR()   __builtin_amdgcn_s_barrier()

// ---------------- prep: fp32->bf16 cvt + LDS-tiled transposes + rowsum zero -----------
// blocks [0,16384): x | [16384,19456): Wqkv^T | [19456,19584): agent*SCALE
// | [19584,20608): Wout^T | [20608,20616): zero rowsum
__global__ __launch_bounds__(256) void k_prep(
    const float* __restrict__ x, const float* __restrict__ Wqkv,
    const float* __restrict__ ag, const float* __restrict__ Wout,
    unsigned short* __restrict__ Xb, unsigned short* __restrict__ WqkvT,
    unsigned short* __restrict__ Ab, unsigned short* __restrict__ WoT,
    float* __restrict__ rowsum)
{
  __shared__ float ldsT[32][33];
  const int tid = threadIdx.x;
  int bx = blockIdx.x;
  if (bx < 16384) {                     // x: 16.7M elems, 4/thread
    size_t i4 = ((size_t)bx * 256 + tid) * 4;
    f32x4 v = *(const f32x4*)&x[i4];
    *(u32x2*)&Xb[i4] = pack4(v[0], v[1], v[2], v[3]);
    return;
  }
  bx -= 16384;
  if (bx < 3072) {                      // WqkvT[j][k] = Wqkv[k][j], 32x32 tiles
    int jt = bx % 96, kt = bx / 96;
    int r32 = tid >> 3, c4 = (tid & 7) * 4;
    f32x4 v = *(const f32x4*)&Wqkv[(size_t)(kt * 32 + r32) * 3072 + jt * 32 + c4];
#pragma unroll
    for (int i = 0; i < 4; i++) ldsT[r32][c4 + i] = v[i];
    __syncthreads();
    float o0 = ldsT[c4 + 0][r32], o1 = ldsT[c4 + 1][r32];
    float o2 = ldsT[c4 + 2][r32], o3 = ldsT[c4 + 3][r32];
    *(u32x2*)&WqkvT[(size_t)(jt * 32 + r32) * 1024 + kt * 32 + c4] = pack4(o0, o1, o2, o3);
    return;
  }
  bx -= 3072;
  if (bx < 128) {                       // agent tokens * SCALE
    size_t i4 = ((size_t)bx * 256 + tid) * 4;
    f32x4 v = *(const f32x4*)&ag[i4];
    *(u32x2*)&Ab[i4] = pack4(v[0] * 0.125f, v[1] * 0.125f, v[2] * 0.125f, v[3] * 0.125f);
    return;
  }
  bx -= 128;
  if (bx < 1024) {                      // WoT[c][d] = Wout[d][c], 32x32 tiles
    int ct = bx % 32, dt = bx / 32;
    int r32 = tid >> 3, c4 = (tid & 7) * 4;
    f32x4 v = *(const f32x4*)&Wout[(size_t)(dt * 32 + r32) * 1024 + ct * 32 + c4];
#pragma unroll
    for (int i = 0; i < 4; i++) ldsT[r32][c4 + i] = v[i];
    __syncthreads();
    float o0 = ldsT[c4 + 0][r32], o1 = ldsT[c4 + 1][r32];
    float o2 = ldsT[c4 + 2][r32], o3 = ldsT[c4 + 3][r32];
    *(u32x2*)&WoT[(size_t)(ct * 32 + r32) * 1024 + dt * 32 + c4] = pack4(o0, o1, o2, o3);
    return;
  }
  bx -= 1024;
  {                                     // zero rowsum (8 blocks x 1024 floats)
    const f32x4 z = {0.f, 0.f, 0.f, 0.f};
    *(f32x4*)&rowsum[((size_t)bx * 256 + tid) * 4] = z;
  }
}

// =====================================================================================
// 256x256-tile pipelined GEMM core (C = A[M,1024] @ Bt[N,1024]^T), bf16.
// 512 threads = 8 waves (2 Mwave x 4 Nwave); per wave 128x64 out; BK=32.
// LDS = ring of 4 K-tiles (A 16KB + B 16KB each) = 128 KiB -> 1 block/CU.
// Schedule per K-tile: 2 phases x {8/4 ds_read, 2 global_load_lds, barrier,
// lgkmcnt(0), setprio(1)+16 MFMA+setprio(0), barrier}; counted vmcnt(8) once
// per K-tile (tiles t+2,t+3 stay in flight across barriers). Ring slot (t+3)&3
// was fully read in iteration t-1 (ds_reads consumed by MFMA before its last
// barrier), so staging it during iteration t is WAR-safe.
// LDS swizzle (T2): 16B-chunk slot = chunk ^ ((row>>1)&3), applied as
// inverse-swizzled GLOBAL source (linear gload_lds dest) + swizzled ds_read.
// swap=1: MFMA A-operand reads the Bt tile (used so Q/K feature dim lands on
// the register-consecutive output-row side).
// =====================================================================================
DEVI void gemm_core_256(const unsigned short* __restrict__ A,
                        const unsigned short* __restrict__ Bt,
                        int row0, int col0, int swap,
                        unsigned short (*lds)[16384], f32x4 acc[8][4])
{
  const int tid = threadIdx.x, lane = tid & 63, w = tid >> 6;
  const int q = lane >> 4, r = lane & 15;
  const int wm = w >> 2, wn = w & 3;
  // ds_read per-lane offset (shorts): row r within frag, swizzled chunk
  const int loff = r * 32 + ((q ^ ((r >> 1) & 3)) << 3);
  // staging: thread covers LDS 16B-slot u = l*512 + tid; row=u>>2, slot=u&3
  const int wslot = w * 512;                              // shorts, wave-uniform LDS base
  const int scol = ((tid & 3) ^ ((tid >> 3) & 3)) << 3;   // inverse-swizzled global chunk
  const int srow = tid >> 2;
  const unsigned short* gA0 = A + (size_t)(row0 + srow) * 1024 + scol;
  const unsigned short* gA1 = gA0 + (size_t)128 * 1024;
  const unsigned short* gB0 = Bt + (size_t)(col0 + srow) * 1024 + scol;
  const unsigned short* gB1 = gB0 + (size_t)128 * 1024;
  const int aoff = (swap ? 8192 : 0) + wm * 4096;
  const int boff = (swap ? 0 : 8192) + wn * 2048;

  const f32x4 z = {0.f, 0.f, 0.f, 0.f};
#pragma unroll
  for (int i = 0; i < 8; i++)
#pragma unroll
    for (int j = 0; j < 4; j++) acc[i][j] = z;

  // prologue: stage K-tiles 0,1,2 into rings 0,1,2 (4 loads each, tile order)
#pragma unroll
  for (int pt = 0; pt < 3; ++pt) {
    unsigned short* lr = &lds[pt][0] + wslot;
    g2l16(gA0 + pt * 32, lr);
    g2l16(gA1 + pt * 32, lr + 4096);
    g2l16(gB0 + pt * 32, lr + 8192);
    g2l16(gB1 + pt * 32, lr + 12288);
  }
  VMCNT8();          // tile 0 landed (tiles 1,2 = newest 8 may fly)
  SBAR();

  for (int t = 0; t < 32; ++t) {
    const unsigned short* rp = &lds[t & 3][0];
    const unsigned short* pA = rp + aoff + loff;
    const unsigned short* pB = rp + boff + loff;
    bf16x8 af[4], bv[4];
    // -------- phase A: frags rt0-3 + all B; stage A-half of tile t+3 --------
#pragma unroll
    for (int rt = 0; rt < 4; rt++) af[rt] = *(const bf16x8*)(pA + rt * 512);
#pragma unroll
    for (int ct = 0; ct < 4; ct++) bv[ct] = *(const bf16x8*)(pB + ct * 512);
    if (t < 29) {
      unsigned short* lr = &lds[(t + 3) & 3][0] + wslot;
      size_t ko = (size_t)(t + 3) * 32;
      g2l16(gA0 + ko, lr);
      g2l16(gA1 + ko, lr + 4096);
    }
    SBAR();
    LGKM0();
    __builtin_amdgcn_s_setprio(1);
#pragma unroll
    for (int rt = 0; rt < 4; rt++)
#pragma unroll
      for (int ct = 0; ct < 4; ct++) MFMA16(acc[rt][ct], af[rt], bv[ct]);
    __builtin_amdgcn_s_setprio(0);
    SBAR();
    // -------- phase B: frags rt4-7 (bv reused); stage B-half; counted vmcnt --------
#pragma unroll
    for (int rt = 0; rt < 4; rt++) af[rt] = *(const bf16x8*)(pA + (rt + 4) * 512);
    if (t < 29) {
      unsigned short* lr = &lds[(t + 3) & 3][0] + wslot;
      size_t ko = (size_t)(t + 3) * 32;
      g2l16(gB0 + ko, lr + 8192);
      g2l16(gB1 + ko, lr + 12288);
    }
    if (t < 29)      { VMCNT8(); }   // tile t+1 landed; t+2,t+3 in flight
    else if (t == 29) { VMCNT4(); }  // tail drain
    else if (t == 30) { VMCNT0(); }
    SBAR();
    LGKM0();
    __builtin_amdgcn_s_setprio(1);
#pragma unroll
    for (int rt = 0; rt < 4; rt++)
#pragma unroll
      for (int ct = 0; ct < 4; ct++) MFMA16(acc[rt + 4][ct], af[rt], bv[ct]);
    __builtin_amdgcn_s_setprio(0);
    SBAR();
  }
}

// ---------------- GEMM1: C[16384,3072] = Xb @ WqkvT^T ; scatter to Q,K,Vt -------------
// grid (x=row 64, y=col 12), 256x256 tiles. Q/K col-blocks: swapped roles ->
// D[j,n], d reg-consecutive. V: D[n,j], n reg-consecutive.
__global__ __launch_bounds__(512, 2) void k_gemm_qkv(
    const unsigned short* __restrict__ A, const unsigned short* __restrict__ Bt,
    unsigned short* __restrict__ Q, unsigned short* __restrict__ Kd,
    unsigned short* __restrict__ Vt)
{
  __shared__ __align__(16) unsigned short lds[4][16384];
  const int tid = threadIdx.x, lane = tid & 63, w = tid >> 6;
  const int q = lane >> 4, r = lane & 15, wm = w >> 2, wn = w & 3;
  const int row0 = blockIdx.x * 256, col0 = blockIdx.y * 256;
  const bool qk = blockIdx.y < 8;

  f32x4 acc[8][4];
  gemm_core_256(A, Bt, row0, col0, qk ? 1 : 0, lds, acc);

  const int b = row0 >> 12, row0b = row0 & 4095;
  if (qk) {   // D[row=j_local, col=n_local]
    unsigned short* dst = (col0 < 1024) ? Q : Kd;
    const int jb = (col0 & 1023) + wm * 128;
#pragma unroll
    for (int rt = 0; rt < 8; rt++)
#pragma unroll
      for (int ct = 0; ct < 4; ct++) {
        int j = jb + rt * 16 + 4 * q;
        int h = j >> 6, d0 = j & 63;
        int n = row0b + wn * 64 + ct * 16 + r;
        u32x2 pk = pack4(acc[rt][ct][0], acc[rt][ct][1], acc[rt][ct][2], acc[rt][ct][3]);
        *(u32x2*)&dst[(((size_t)(b * 16 + h)) * 4096 + n) * 64 + d0] = pk;
      }
  } else {    // D[row=n, col=j]; pack 4 consecutive n into Vt[b,h,d,n]
    const int jb = (col0 - 2048) + wn * 64;
#pragma unroll
    for (int rt = 0; rt < 8; rt++)
#pragma unroll
      for (int ct = 0; ct < 4; ct++) {
        int j = jb + ct * 16 + r;
        int h = j >> 6, d = j & 63;
        int n = row0b + wm * 128 + rt * 16 + 4 * q;
        u32x2 pk = pack4(acc[rt][ct][0], acc[rt][ct][1], acc[rt][ct][2], acc[rt][ct][3]);
        *(u32x2*)&Vt[(((size_t)(b * 16 + h)) * 64 + d) * 4096 + n] = pk;
      }
  }
}

// ------- qk: fused qa (softmax over m -> QA[b,h,n,m]) + ak (mask+exp -> E[b,h,m,n]) ---
__global__ __launch_bounds__(256, 2) void k_qk(
    const unsigned short* __restrict__ Q, const unsigned short* __restrict__ Kd,
    const unsigned short* __restrict__ Ab, const int* __restrict__ mask,
    unsigned short* __restrict__ QA, unsigned short* __restrict__ E,
    float* __restrict__ rowsum)
{
  const int tid = threadIdx.x, lane = tid & 63, w = tid >> 6;
  const int q = lane >> 4, r = lane & 15, wr = w >> 1, wc = w & 1;
  const int nt = blockIdx.x, h = blockIdx.y, b = blockIdx.z;
  const unsigned short* Qb = Q + (((size_t)(b * 16 + h)) * 4096 + nt * 128) * 64;
  const unsigned short* Kb = Kd + (((size_t)(b * 16 + h)) * 4096 + nt * 128) * 64;
  const unsigned short* Ah = Ab + (size_t)h * 8192;
  __shared__ float rs[2][128];
  const f32x4 z = {0.f, 0.f, 0.f, 0.f};

  // ================= qa part: D[m,n] (A=agent rows m, B=Q rows n) =================
  {
    f32x4 acc[4][4];
#pragma unroll
    for (int i = 0; i < 4; i++)
#pragma unroll
      for (int j = 0; j < 4; j++) acc[i][j] = z;
#pragma unroll
    for (int ks = 0; ks < 2; ks++) {
      bf16x8 af[4], bv[4];
#pragma unroll
      for (int rt = 0; rt < 4; rt++) af[rt] = ldg8(Ah + (size_t)(64 * wr + 16 * rt + r) * 64 + ks * 32 + q * 8);
#pragma unroll
      for (int ct = 0; ct < 4; ct++) bv[ct] = ldg8(Qb + (size_t)(64 * wc + 16 * ct + r) * 64 + ks * 32 + q * 8);
#pragma unroll
      for (int rt = 0; rt < 4; rt++)
#pragma unroll
        for (int ct = 0; ct < 4; ct++) MFMA16(acc[rt][ct], af[rt], bv[ct]);
    }
    float cs[4];
#pragma unroll
    for (int ct = 0; ct < 4; ct++) {
      float s = 0.f;
#pragma unroll
      for (int rt = 0; rt < 4; rt++)
#pragma unroll
        for (int reg = 0; reg < 4; reg++) {
          float e = __expf(acc[rt][ct][reg]);
          acc[rt][ct][reg] = e; s += e;
        }
      s += __shfl_xor(s, 16); s += __shfl_xor(s, 32);
      cs[ct] = s;
    }
    if (q == 0) {
#pragma unroll
      for (int ct = 0; ct < 4; ct++) rs[wr][64 * wc + 16 * ct + r] = cs[ct];
    }
    __syncthreads();
#pragma unroll
    for (int ct = 0; ct < 4; ct++) {
      int nl = 64 * wc + 16 * ct + r;
      float inv = 1.0f / (rs[0][nl] + rs[1][nl]);
      int n = nt * 128 + nl;
      size_t base = (((size_t)(b * 16 + h)) * 4096 + n) * 128;
#pragma unroll
      for (int rt = 0; rt < 4; rt++) {
        int m0 = 64 * wr + 16 * rt + 4 * q;
        u32x2 pk = pack4(acc[rt][ct][0] * inv, acc[rt][ct][1] * inv,
                         acc[rt][ct][2] * inv, acc[rt][ct][3] * inv);
        *(u32x2*)&QA[base + m0] = pk;
      }
    }
  }
  __syncthreads();   // rs WAR hazard between sections

  // ================= ak part: D[n,m] (A=K rows n, B=agent rows m) =================
  {
    f32x4 acc[4][4];
#pragma unroll
    for (int i = 0; i < 4; i++)
#pragma unroll
      for (int j = 0; j < 4; j++) acc[i][j] = z;
#pragma unroll
    for (int ks = 0; ks < 2; ks++) {
      bf16x8 af[4], bv[4];
#pragma unroll
      for (int rt = 0; rt < 4; rt++) af[rt] = ldg8(Kb + (size_t)(64 * wr + 16 * rt + r) * 64 + ks * 32 + q * 8);
#pragma unroll
      for (int ct = 0; ct < 4; ct++) bv[ct] = ldg8(Ah + (size_t)(64 * wc + 16 * ct + r) * 64 + ks * 32 + q * 8);
#pragma unroll
      for (int rt = 0; rt < 4; rt++)
#pragma unroll
        for (int ct = 0; ct < 4; ct++) MFMA16(acc[rt][ct], af[rt], bv[ct]);
    }
    float cs[4] = {0.f, 0.f, 0.f, 0.f};
#pragma unroll
    for (int rt = 0; rt < 4; rt++) {
      const int4 mkv = *(const int4*)&mask[b * 4096 + nt * 128 + 64 * wr + 16 * rt + 4 * q];
      int mka[4] = {mkv.x, mkv.y, mkv.z, mkv.w};
#pragma unroll
      for (int ct = 0; ct < 4; ct++) {
#pragma unroll
        for (int reg = 0; reg < 4; reg++) {
          float e = mka[reg] ? __expf(acc[rt][ct][reg]) : 0.0f;
          acc[rt][ct][reg] = e; cs[ct] += e;
        }
      }
    }
#pragma unroll
    for (int ct = 0; ct < 4; ct++) {
      float s = cs[ct];
      s += __shfl_xor(s, 16); s += __shfl_xor(s, 32);
      cs[ct] = s;
    }
    if (q == 0) {
#pragma unroll
      for (int ct = 0; ct < 4; ct++) rs[wr][64 * wc + 16 * ct + r] = cs[ct];
    }
#pragma unroll
    for (int ct = 0; ct < 4; ct++) {
      int m = 64 * wc + 16 * ct + r;
      size_t base = (((size_t)(b * 16 + h)) * 128 + m) * 4096;
#pragma unroll
      for (int rt = 0; rt < 4; rt++) {
        int n0 = nt * 128 + 64 * wr + 16 * rt + 4 * q;
        u32x2 pk = pack4(acc[rt][ct][0], acc[rt][ct][1], acc[rt][ct][2], acc[rt][ct][3]);
        *(u32x2*)&E[base + n0] = pk;
      }
    }
    __syncthreads();
    if (tid < 128) atomicAdd(&rowsum[(b * 16 + h) * 128 + tid], rs[0][tid] + rs[1][tid]);
  }
}

// ---- mix: MIX[g,m,n] = sum_h Wak[g,h]*E[h,m,n]/rowsum[h,m]  (4 elems/thread, 8B IO) --
__global__ __launch_bounds__(256) void k_mix(
    const unsigned short* __restrict__ E, const float* __restrict__ rowsum,
    const float* __restrict__ Wak, unsigned short* __restrict__ MIX)
{
  const int tid = threadIdx.x;
  const int m = blockIdx.y, b = blockIdx.z;
  __shared__ float wv[256];
  __shared__ float inv[16];
  wv[tid] = Wak[tid];
  if (tid < 16) inv[tid] = 1.0f / rowsum[(b * 16 + tid) * 128 + m];
  __syncthreads();
  const int n0 = (blockIdx.x * 256 + tid) * 4;
  float p[16][4];
#pragma unroll
  for (int h = 0; h < 16; h++) {
    u32x2 v = *(const u32x2*)&E[(((size_t)(b * 16 + h)) * 128 + m) * 4096 + n0];
    float iv = inv[h];
    p[h][0] = bf2f((unsigned short)(v.x & 0xffff)) * iv;
    p[h][1] = bf2f((unsigned short)(v.x >> 16)) * iv;
    p[h][2] = bf2f((unsigned short)(v.y & 0xffff)) * iv;
    p[h][3] = bf2f((unsigned short)(v.y >> 16)) * iv;
  }
#pragma unroll
  for (int g = 0; g < 16; g++) {
    float s0 = 0.f, s1 = 0.f, s2 = 0.f, s3 = 0.f;
#pragma unroll
    for (int h = 0; h < 16; h++) {
      float wgh = wv[g * 16 + h];
      s0 += wgh * p[h][0]; s1 += wgh * p[h][1]; s2 += wgh * p[h][2]; s3 += wgh * p[h][3];
    }
    *(u32x2*)&MIX[(((size_t)(b * 16 + g)) * 128 + m) * 4096 + n0] = pack4(s0, s1, s2, s3);
  }
}

// ------ k_ao: partial AO_T planes P[kc][b,g,d,m] = MIX[b,g] @ V[b,g] (k-chunk) --------
__global__ __launch_bounds__(256) void k_ao(
    const unsigned short* __restrict__ MIX, const unsigned short* __restrict__ Vt,
    float* __restrict__ P)
{
  const int tid = threadIdx.x, lane = tid & 63, w4 = tid >> 6;
  const int q = lane >> 4, r = lane & 15;
  const int kc = blockIdx.x, g = blockIdx.y, b = blockIdx.z;
  const unsigned short* Abase = MIX + ((size_t)(b * 16 + g)) * 128 * 4096;
  const unsigned short* Bbase = Vt + ((size_t)(b * 16 + g)) * 64 * 4096;
  f32x4 acc[2][4];
  const f32x4 z = {0.f, 0.f, 0.f, 0.f};
#pragma unroll
  for (int i = 0; i < 2; i++)
#pragma unroll
    for (int j = 0; j < 4; j++) acc[i][j] = z;
  for (int n = kc * 512; n < kc * 512 + 512; n += 32) {
    bf16x8 af[2], bv[4];
#pragma unroll
    for (int rt = 0; rt < 2; rt++) af[rt] = ldg8(Abase + (size_t)(32 * w4 + 16 * rt + r) * 4096 + n + q * 8);
#pragma unroll
    for (int ct = 0; ct < 4; ct++) bv[ct] = ldg8(Bbase + (size_t)(16 * ct + r) * 4096 + n + q * 8);
#pragma unroll
    for (int rt = 0; rt < 2; rt++)
#pragma unroll
      for (int ct = 0; ct < 4; ct++) MFMA16(acc[rt][ct], af[rt], bv[ct]);
  }
  float* Pp = P + (size_t)kc * 524288 + ((size_t)(b * 16 + g)) * 8192;
#pragma unroll
  for (int rt = 0; rt < 2; rt++)
#pragma unroll
    for (int ct = 0; ct < 4; ct++) {
      int m0 = 32 * w4 + 16 * rt + 4 * q, d = 16 * ct + r;
      *(f32x4*)&Pp[(size_t)d * 128 + m0] = acc[rt][ct];   // regs = consecutive m
    }
}

// ------ aored: AOt = sum_kc P[kc]  (524288 fp32) --------------------------------------
__global__ __launch_bounds__(256) void k_aored(
    const float* __restrict__ P, float* __restrict__ AOt)
{
  size_t i = ((size_t)blockIdx.x * 256 + threadIdx.x) * 4;
  f32x4 s = *(const f32x4*)&P[i];
#pragma unroll
  for (int kc = 1; kc < 8; kc++) {
    f32x4 v = *(const f32x4*)&P[(size_t)kc * 524288 + i];
    s[0] += v[0]; s[1] += v[1]; s[2] += v[2]; s[3] += v[3];
  }
  *(f32x4*)&AOt[i] = s;
}

// ---- mixqa: QAmix[g,plane] = sum_h Wqa[g,h]*QA[h,plane]  (4 elems/thread, 8B IO) -----
__global__ __launch_bounds__(256) void k_mixqa(
    const unsigned short* __restrict__ QA, const float* __restrict__ Wqa,
    unsigned short* __restrict__ QAmix)
{
  const int tid = threadIdx.x;
  const int b = blockIdx.y;
  __shared__ float wv[256];
  wv[tid] = Wqa[tid];
  __syncthreads();
  const size_t i0 = ((size_t)blockIdx.x * 256 + tid) * 4;   // plane 524288 elems
  float p[16][4];
#pragma unroll
  for (int h = 0; h < 16; h++) {
    u32x2 v = *(const u32x2*)&QA[((size_t)(b * 16 + h)) * 524288 + i0];
    p[h][0] = bf2f((unsigned short)(v.x & 0xffff));
    p[h][1] = bf2f((unsigned short)(v.x >> 16));
    p[h][2] = bf2f((unsigned short)(v.y & 0xffff));
    p[h][3] = bf2f((unsigned short)(v.y >> 16));
  }
#pragma unroll
  for (int g = 0; g < 16; g++) {
    float s0 = 0.f, s1 = 0.f, s2 = 0.f, s3 = 0.f;
#pragma unroll
    for (int h = 0; h < 16; h++) {
      float wgh = wv[g * 16 + h];
      s0 += wgh * p[h][0]; s1 += wgh * p[h][1]; s2 += wgh * p[h][2]; s3 += wgh * p[h][3];
    }
    *(u32x2*)&QAmix[((size_t)(b * 16 + g)) * 524288 + i0] = pack4(s0, s1, s2, s3);
  }
}

// ---- o1: swapped roles -> D[d,n]; out1[b,n,g*64+d] 8B stores; reads AO_T fp32 --------
__global__ __launch_bounds__(256) void k_o1(
    const unsigned short* __restrict__ QAmix, const float* __restrict__ AOt,
    unsigned short* __restrict__ out1)
{
  const int tid = threadIdx.x, lane = tid & 63, w4 = tid >> 6;
  const int q = lane >> 4, r = lane & 15;
  const int nt = blockIdx.x, g = blockIdx.y, b = blockIdx.z;
  const unsigned short* Bbase = QAmix + (((size_t)(b * 16 + g)) * 4096 + nt * 128) * 128;
  const float* Abase = AOt + ((size_t)(b * 16 + g)) * 8192;   // [d][m]
  f32x4 acc[4][2];
  const f32x4 z = {0.f, 0.f, 0.f, 0.f};
#pragma unroll
  for (int i = 0; i < 4; i++)
#pragma unroll
    for (int j = 0; j < 2; j++) acc[i][j] = z;
#pragma unroll
  for (int ks = 0; ks < 4; ks++) {
    bf16x8 af[4], bv[2];
#pragma unroll
    for (int rt = 0; rt < 4; rt++) {
      const float* p = Abase + (size_t)(16 * rt + r) * 128 + ks * 32 + q * 8;
      f32x4 f0 = *(const f32x4*)p;
      f32x4 f1 = *(const f32x4*)(p + 4);
      bf16x8 t;
#pragma unroll
      for (int jj = 0; jj < 4; jj++) { t[jj] = (__bf16)f0[jj]; t[4 + jj] = (__bf16)f1[jj]; }
      af[rt] = t;
    }
#pragma unroll
    for (int ct = 0; ct < 2; ct++)
      bv[ct] = ldg8(Bbase + (size_t)(32 * w4 + 16 * ct + r) * 128 + ks * 32 + q * 8);
#pragma unroll
    for (int rt = 0; rt < 4; rt++)
#pragma unroll
      for (int ct = 0; ct < 2; ct++) MFMA16(acc[rt][ct], af[rt], bv[ct]);
  }
#pragma unroll
  for (int ct = 0; ct < 2; ct++) {
    int n = nt * 128 + 32 * w4 + 16 * ct + r;
    size_t base = ((size_t)b * 4096 + n) * 1024 + g * 64;
#pragma unroll
    for (int rt = 0; rt < 4; rt++) {
      int d0 = 16 * rt + 4 * q;
      u32x2 pk = pack4(acc[rt][ct][0], acc[rt][ct][1], acc[rt][ct][2], acc[rt][ct][3]);
      *(u32x2*)&out1[base + d0] = pk;
    }
  }
}

// ------- fin2: out[16384,1024] = out1 @ WoT^T, mask rows, fp32; 256x256 tiles ---------
__global__ __launch_bounds__(512, 2) void k_fin2(
    const unsigned short* __restrict__ A, const unsigned short* __restrict__ Bt,
    const int* __restrict__ mask, float* __restrict__ out)
{
  __shared__ __align__(16) unsigned short lds[4][16384];
  const int tid = threadIdx.x, lane = tid & 63, w = tid >> 6;
  const int q = lane >> 4, r = lane & 15, wm = w >> 2, wn = w & 3;
  const int row0 = blockIdx.x * 256, col0 = blockIdx.y * 256;

  f32x4 acc[8][4];
  gemm_core_256(A, Bt, row0, col0, 0, lds, acc);

#pragma unroll
  for (int rt = 0; rt < 8; rt++) {
    const int4 mkv = *(const int4*)&mask[row0 + wm * 128 + rt * 16 + 4 * q];
    int mka[4] = {mkv.x, mkv.y, mkv.z, mkv.w};
#pragma unroll
    for (int reg = 0; reg < 4; reg++) {
      int row = row0 + wm * 128 + rt * 16 + 4 * q + reg;
#pragma unroll
      for (int ct = 0; ct < 4; ct++) {
        int c = col0 + wn * 64 + ct * 16 + r;
        out[(size_t)row * 1024 + c] = mka[reg] ? acc[rt][ct][reg] : 0.0f;
      }
    }
  }
}

// =====================================================================================
extern "C" void kernel_launch(void* const* d_in, const int* in_sizes, int n_in,
                              void* d_out, int out_size, void* d_ws, size_t ws_size,
                              hipStream_t stream) {
  const float* x    = (const float*)d_in[0];
  const int*   mask = (const int*)d_in[1];
  const float* Wqkv = (const float*)d_in[2];
  const float* ag   = (const float*)d_in[3];
  const float* Wqa  = (const float*)d_in[4];
  const float* Wak  = (const float*)d_in[5];
  const float* Wout = (const float*)d_in[6];
  float* out = (float*)d_out;
  char* ws = (char*)d_ws;

  // workspace layout, lifetime-overlapped; total 239,370,240 B (unchanged)
  unsigned short* QA    = (unsigned short*)(ws + 0);           // [qk -> mixqa]
  unsigned short* QQ    = (unsigned short*)(ws + 67108864);    // Q [gemm -> qk]
  unsigned short* KK    = (unsigned short*)(ws + 67108864 + 33554432);  // K [gemm -> qk]
  unsigned short* MIX   = QQ;                                  // [mix -> ao] (spans QQ+KK)
  unsigned short* out1  = QQ;                                  // [o1 -> fin2]
  unsigned short* VT    = (unsigned short*)(ws + 134217728);   // Vt [gemm -> ao]
  unsigned short* Xb    = (unsigned short*)(ws + 167772160);   // [prep -> gemm]
  unsigned short* WqkvT = (unsigned short*)(ws + 167772160 + 33554432);
  unsigned short* E     = Xb;                                  // [qk -> mix]
  float*          Ppart = (float*)Xb;                          // 16MB [ao -> aored] (E dead)
  unsigned short* QAmix = Xb;                                  // [mixqa -> o1] (Ppart dead)
  char* sm = ws + 234881024;
  unsigned short* Ab  = (unsigned short*)(sm);                 // 256 KB
  unsigned short* WoT = (unsigned short*)(sm + 262144);        // 2 MB
  float* rowsum = (float*)(sm + 262144 + 2097152);             // 32 KB
  float* AOt    = (float*)(sm + 262144 + 2097152 + 32768);     // 2 MB [b,g,d,m] fp32

  k_prep<<<20616, 256, 0, stream>>>(x, Wqkv, ag, Wout, Xb, WqkvT, Ab, WoT, rowsum);
  k_gemm_qkv<<<dim3(64, 12), 512, 0, stream>>>(Xb, WqkvT, QQ, KK, VT);
  k_qk<<<dim3(32, 16, 4), 256, 0, stream>>>(QQ, KK, Ab, mask, QA, E, rowsum);
  k_mix<<<dim3(4, 128, 4), 256, 0, stream>>>(E, rowsum, Wak, MIX);
  k_ao<<<dim3(8, 16, 4), 256, 0, stream>>>(MIX, VT, Ppart);
  k_aored<<<512, 256, 0, stream>>>(Ppart, AOt);
  k_mixqa<<<dim3(512, 4), 256, 0, stream>>>(QA, Wqa, QAmix);
  k_o1<<<dim3(32, 16, 4), 256, 0, stream>>>(QAmix, AOt, out1);
  k_fin2<<<dim3(64, 4), 512, 0, stream>>>(out1, WoT, mask, out);
}

// Round 3
// 462.542 us; speedup vs baseline: 1.0856x; 1.0119x over previous
//
#include <hip/hip_runtime.h>
#include <stdint.h>

#define DEVI __device__ __forceinline__

typedef __bf16 bf16x8 __attribute__((ext_vector_type(8)));
typedef float  f32x4  __attribute__((ext_vector_type(4)));
typedef unsigned int u32x2 __attribute__((ext_vector_type(2)));

// B=4, N=4096, DIM=1024, H=16, D=64, M=128, DIM_INNER=1024, SCALE=0.125

DEVI unsigned short f2bf(float f) {  // RNE f32->bf16
  union { float f; unsigned int u; } c; c.f = f;
  return (unsigned short)((c.u + 0x7fffu + ((c.u >> 16) & 1u)) >> 16);
}
DEVI float bf2f(unsigned short s) {
  union { unsigned int u; float f; } c; c.u = ((unsigned int)s) << 16;
  return c.f;
}
DEVI u32x2 pack4(float a, float b, float c, float d) {
  u32x2 r;
  r.x = (unsigned)f2bf(a) | ((unsigned)f2bf(b) << 16);
  r.y = (unsigned)f2bf(c) | ((unsigned)f2bf(d) << 16);
  return r;
}
DEVI bf16x8 ldg8(const unsigned short* p) { return *(const bf16x8*)p; }

DEVI void g2l16(const void* g, void* l) {
  __builtin_amdgcn_global_load_lds(
      (const __attribute__((address_space(1))) unsigned int*)g,
      (__attribute__((address_space(3))) unsigned int*)l, 16, 0, 0);
}

#define MFMA16(acc, a, b) acc = __builtin_amdgcn_mfma_f32_16x16x32_bf16((a), (b), (acc), 0, 0, 0)

// Bare waits + bare s_barrier (no memory clobbers; round-1/2 post-mortem).
#define VMCNT8() asm volatile("s_waitcnt vmcnt(8)")
#define VMCNT4() asm volatile("s_waitcnt vmcnt(4)")
#define VMCNT0() asm volatile("s_waitcnt vmcnt(0)")
#define SBAR()   __builtin_amdgcn_s_barrier()
#define SCHEDB() __builtin_amdgcn_sched_barrier(0)

// ---------------- prep: fp32->bf16 cvt + LDS-tiled transposes + rowsum zero -----------
// blocks [0,16384): x | [16384,19456): Wqkv^T | [19456,19584): agent*SCALE
// | [19584,20608): Wout^T | [20608,20616): zero rowsum
__global__ __launch_bounds__(256) void k_prep(
    const float* __restrict__ x, const float* __restrict__ Wqkv,
    const float* __restrict__ ag, const float* __restrict__ Wout,
    unsigned short* __restrict__ Xb, unsigned short* __restrict__ WqkvT,
    unsigned short* __restrict__ Ab, unsigned short* __restrict__ WoT,
    float* __restrict__ rowsum)
{
  __shared__ float ldsT[32][33];
  const int tid = threadIdx.x;
  int bx = blockIdx.x;
  if (bx < 16384) {                     // x: 16.7M elems, 4/thread
    size_t i4 = ((size_t)bx * 256 + tid) * 4;
    f32x4 v = *(const f32x4*)&x[i4];
    *(u32x2*)&Xb[i4] = pack4(v[0], v[1], v[2], v[3]);
    return;
  }
  bx -= 16384;
  if (bx < 3072) {                      // WqkvT[j][k] = Wqkv[k][j], 32x32 tiles
    int jt = bx % 96, kt = bx / 96;
    int r32 = tid >> 3, c4 = (tid & 7) * 4;
    f32x4 v = *(const f32x4*)&Wqkv[(size_t)(kt * 32 + r32) * 3072 + jt * 32 + c4];
#pragma unroll
    for (int i = 0; i < 4; i++) ldsT[r32][c4 + i] = v[i];
    __syncthreads();
    float o0 = ldsT[c4 + 0][r32], o1 = ldsT[c4 + 1][r32];
    float o2 = ldsT[c4 + 2][r32], o3 = ldsT[c4 + 3][r32];
    *(u32x2*)&WqkvT[(size_t)(jt * 32 + r32) * 1024 + kt * 32 + c4] = pack4(o0, o1, o2, o3);
    return;
  }
  bx -= 3072;
  if (bx < 128) {                       // agent tokens * SCALE
    size_t i4 = ((size_t)bx * 256 + tid) * 4;
    f32x4 v = *(const f32x4*)&ag[i4];
    *(u32x2*)&Ab[i4] = pack4(v[0] * 0.125f, v[1] * 0.125f, v[2] * 0.125f, v[3] * 0.125f);
    return;
  }
  bx -= 128;
  if (bx < 1024) {                      // WoT[c][d] = Wout[d][c], 32x32 tiles
    int ct = bx % 32, dt = bx / 32;
    int r32 = tid >> 3, c4 = (tid & 7) * 4;
    f32x4 v = *(const f32x4*)&Wout[(size_t)(dt * 32 + r32) * 1024 + ct * 32 + c4];
#pragma unroll
    for (int i = 0; i < 4; i++) ldsT[r32][c4 + i] = v[i];
    __syncthreads();
    float o0 = ldsT[c4 + 0][r32], o1 = ldsT[c4 + 1][r32];
    float o2 = ldsT[c4 + 2][r32], o3 = ldsT[c4 + 3][r32];
    *(u32x2*)&WoT[(size_t)(ct * 32 + r32) * 1024 + dt * 32 + c4] = pack4(o0, o1, o2, o3);
    return;
  }
  bx -= 1024;
  {                                     // zero rowsum (8 blocks x 1024 floats)
    const f32x4 z = {0.f, 0.f, 0.f, 0.f};
    *(f32x4*)&rowsum[((size_t)bx * 256 + tid) * 4] = z;
  }
}

// =====================================================================================
// 256x256-tile pipelined GEMM core (C = A[M,1024] @ Bt[N,1024]^T), bf16.
// 512 threads = 8 waves (2 Mwave x 4 Nwave); per wave 128x64 out; BK=32.
// LDS = ring of 4 K-tiles (A 16KB + B 16KB each) = 128 KiB -> 1 block/CU.
//
// ONE barrier per phase (round-3 change; was 2):
//   phase: { ds_read frags (pre-barrier) ; sched_barrier(0) ; [vmcnt in B] ;
//            s_barrier ; [stage tile t+3 in A] ; setprio(1) 16xMFMA setprio(0) }
// No blanket lgkmcnt(0): compiler emits per-operand lgkm waits, so each wave
// starts MFMA as soon as ITS reads land -> late waves' LDS drain overlaps
// early waves' MFMA; post-MFMA waves issue next-phase reads under others' MFMA.
// WAR safety (ring-4, stage-ahead-3): stage at iter t writes slot (t+3)&3 =
// (t-1)&3. All reads of that slot (iter t-1) are lgkm-drained before each
// wave's MFMA(B,t-1), hence before it reaches BAR(A,t); stage is issued only
// after BAR(A,t). RAW safety: vmcnt(8) at B(t) drains tile t+1 (outstanding
// <=12: tiles t+1,t+2,t+3) before the barrier that precedes its first read.
// Tail: vmcnt 4 at t==29, 0 at t==30.
// LDS swizzle (T2): 16B-chunk slot = chunk ^ ((row>>1)&3), applied as
// inverse-swizzled GLOBAL source (linear gload_lds dest) + swizzled ds_read.
// swap=1: MFMA A-operand reads the Bt tile (Q/K: feature dim on output-row side).
// =====================================================================================
DEVI void gemm_core_256(const unsigned short* __restrict__ A,
                        const unsigned short* __restrict__ Bt,
                        int row0, int col0, int swap,
                        unsigned short (*lds)[16384], f32x4 acc[8][4])
{
  const int tid = threadIdx.x, lane = tid & 63, w = tid >> 6;
  const int q = lane >> 4, r = lane & 15;
  const int wm = w >> 2, wn = w & 3;
  // ds_read per-lane offset (shorts): row r within frag, swizzled chunk
  const int loff = r * 32 + ((q ^ ((r >> 1) & 3)) << 3);
  // staging: thread covers LDS 16B-slot u = l*512 + tid; row=u>>2, slot=u&3
  const int wslot = w * 512;                              // shorts, wave-uniform LDS base
  const int scol = ((tid & 3) ^ ((tid >> 3) & 3)) << 3;   // inverse-swizzled global chunk
  const int srow = tid >> 2;
  const unsigned short* gA0 = A + (size_t)(row0 + srow) * 1024 + scol;
  const unsigned short* gA1 = gA0 + (size_t)128 * 1024;
  const unsigned short* gB0 = Bt + (size_t)(col0 + srow) * 1024 + scol;
  const unsigned short* gB1 = gB0 + (size_t)128 * 1024;
  const int aoff = (swap ? 8192 : 0) + wm * 4096;
  const int boff = (swap ? 0 : 8192) + wn * 2048;

  const f32x4 z = {0.f, 0.f, 0.f, 0.f};
#pragma unroll
  for (int i = 0; i < 8; i++)
#pragma unroll
    for (int j = 0; j < 4; j++) acc[i][j] = z;

  // prologue: stage K-tiles 0,1,2 into rings 0,1,2 (4 loads each, tile order)
#pragma unroll
  for (int pt = 0; pt < 3; ++pt) {
    unsigned short* lr = &lds[pt][0] + wslot;
    g2l16(gA0 + pt * 32, lr);
    g2l16(gA1 + pt * 32, lr + 4096);
    g2l16(gB0 + pt * 32, lr + 8192);
    g2l16(gB1 + pt * 32, lr + 12288);
  }
  VMCNT8();          // tile 0 landed (tiles 1,2 = newest 8 may fly)
  SBAR();

  for (int t = 0; t < 32; ++t) {
    const unsigned short* rp = &lds[t & 3][0];
    const unsigned short* pA = rp + aoff + loff;
    const unsigned short* pB = rp + boff + loff;
    bf16x8 af[4], bv[4];
    // -------- phase A: bv first (first MFMA's operands land earliest) --------
#pragma unroll
    for (int ct = 0; ct < 4; ct++) bv[ct] = *(const bf16x8*)(pB + ct * 512);
#pragma unroll
    for (int rt = 0; rt < 4; rt++) af[rt] = *(const bf16x8*)(pA + rt * 512);
    SCHEDB();
    SBAR();
    if (t < 29) {    // stage full tile t+3 after the barrier (WAR-safe point)
      unsigned short* lr = &lds[(t + 3) & 3][0] + wslot;
      size_t ko = (size_t)(t + 3) * 32;
      g2l16(gA0 + ko, lr);
      g2l16(gA1 + ko, lr + 4096);
      g2l16(gB0 + ko, lr + 8192);
      g2l16(gB1 + ko, lr + 12288);
    }
    __builtin_amdgcn_s_setprio(1);
#pragma unroll
    for (int rt = 0; rt < 4; rt++)
#pragma unroll
      for (int ct = 0; ct < 4; ct++) MFMA16(acc[rt][ct], af[rt], bv[ct]);
    __builtin_amdgcn_s_setprio(0);
    // -------- phase B: frags rt4-7 (bv reused); counted vmcnt; one barrier --------
#pragma unroll
    for (int rt = 0; rt < 4; rt++) af[rt] = *(const bf16x8*)(pA + (rt + 4) * 512);
    SCHEDB();
    if (t < 29)       { VMCNT8(); }  // drains tile t+1 (needed after this barrier)
    else if (t == 29) { VMCNT4(); }  // tail drain: tile 30
    else if (t == 30) { VMCNT0(); }  // tail drain: tile 31
    SBAR();
    __builtin_amdgcn_s_setprio(1);
#pragma unroll
    for (int rt = 0; rt < 4; rt++)
#pragma unroll
      for (int ct = 0; ct < 4; ct++) MFMA16(acc[rt + 4][ct], af[rt], bv[ct]);
    __builtin_amdgcn_s_setprio(0);
  }
}

// ---------------- GEMM1: C[16384,3072] = Xb @ WqkvT^T ; scatter to Q,K,Vt -------------
// grid (x=row 64, y=col 12), 256x256 tiles. Q/K col-blocks: swapped roles ->
// D[j,n], d reg-consecutive. V: D[n,j], n reg-consecutive.
__global__ __launch_bounds__(512, 2) void k_gemm_qkv(
    const unsigned short* __restrict__ A, const unsigned short* __restrict__ Bt,
    unsigned short* __restrict__ Q, unsigned short* __restrict__ Kd,
    unsigned short* __restrict__ Vt)
{
  __shared__ __align__(16) unsigned short lds[4][16384];
  const int tid = threadIdx.x, lane = tid & 63, w = tid >> 6;
  const int q = lane >> 4, r = lane & 15, wm = w >> 2, wn = w & 3;
  const int row0 = blockIdx.x * 256, col0 = blockIdx.y * 256;
  const bool qk = blockIdx.y < 8;

  f32x4 acc[8][4];
  gemm_core_256(A, Bt, row0, col0, qk ? 1 : 0, lds, acc);

  const int b = row0 >> 12, row0b = row0 & 4095;
  if (qk) {   // D[row=j_local, col=n_local]
    unsigned short* dst = (col0 < 1024) ? Q : Kd;
    const int jb = (col0 & 1023) + wm * 128;
#pragma unroll
    for (int rt = 0; rt < 8; rt++)
#pragma unroll
      for (int ct = 0; ct < 4; ct++) {
        int j = jb + rt * 16 + 4 * q;
        int h = j >> 6, d0 = j & 63;
        int n = row0b + wn * 64 + ct * 16 + r;
        u32x2 pk = pack4(acc[rt][ct][0], acc[rt][ct][1], acc[rt][ct][2], acc[rt][ct][3]);
        *(u32x2*)&dst[(((size_t)(b * 16 + h)) * 4096 + n) * 64 + d0] = pk;
      }
  } else {    // D[row=n, col=j]; pack 4 consecutive n into Vt[b,h,d,n]
    const int jb = (col0 - 2048) + wn * 64;
#pragma unroll
    for (int rt = 0; rt < 8; rt++)
#pragma unroll
      for (int ct = 0; ct < 4; ct++) {
        int j = jb + ct * 16 + r;
        int h = j >> 6, d = j & 63;
        int n = row0b + wm * 128 + rt * 16 + 4 * q;
        u32x2 pk = pack4(acc[rt][ct][0], acc[rt][ct][1], acc[rt][ct][2], acc[rt][ct][3]);
        *(u32x2*)&Vt[(((size_t)(b * 16 + h)) * 64 + d) * 4096 + n] = pk;
      }
  }
}

// ------- qk: fused qa (softmax over m -> QA[b,h,n,m]) + ak (mask+exp -> E[b,h,m,n]) ---
__global__ __launch_bounds__(256, 2) void k_qk(
    const unsigned short* __restrict__ Q, const unsigned short* __restrict__ Kd,
    const unsigned short* __restrict__ Ab, const int* __restrict__ mask,
    unsigned short* __restrict__ QA, unsigned short* __restrict__ E,
    float* __restrict__ rowsum)
{
  const int tid = threadIdx.x, lane = tid & 63, w = tid >> 6;
  const int q = lane >> 4, r = lane & 15, wr = w >> 1, wc = w & 1;
  const int nt = blockIdx.x, h = blockIdx.y, b = blockIdx.z;
  const unsigned short* Qb = Q + (((size_t)(b * 16 + h)) * 4096 + nt * 128) * 64;
  const unsigned short* Kb = Kd + (((size_t)(b * 16 + h)) * 4096 + nt * 128) * 64;
  const unsigned short* Ah = Ab + (size_t)h * 8192;
  __shared__ float rs[2][128];
  const f32x4 z = {0.f, 0.f, 0.f, 0.f};

  // ================= qa part: D[m,n] (A=agent rows m, B=Q rows n) =================
  {
    f32x4 acc[4][4];
#pragma unroll
    for (int i = 0; i < 4; i++)
#pragma unroll
      for (int j = 0; j < 4; j++) acc[i][j] = z;
#pragma unroll
    for (int ks = 0; ks < 2; ks++) {
      bf16x8 af[4], bv[4];
#pragma unroll
      for (int rt = 0; rt < 4; rt++) af[rt] = ldg8(Ah + (size_t)(64 * wr + 16 * rt + r) * 64 + ks * 32 + q * 8);
#pragma unroll
      for (int ct = 0; ct < 4; ct++) bv[ct] = ldg8(Qb + (size_t)(64 * wc + 16 * ct + r) * 64 + ks * 32 + q * 8);
#pragma unroll
      for (int rt = 0; rt < 4; rt++)
#pragma unroll
        for (int ct = 0; ct < 4; ct++) MFMA16(acc[rt][ct], af[rt], bv[ct]);
    }
    float cs[4];
#pragma unroll
    for (int ct = 0; ct < 4; ct++) {
      float s = 0.f;
#pragma unroll
      for (int rt = 0; rt < 4; rt++)
#pragma unroll
        for (int reg = 0; reg < 4; reg++) {
          float e = __expf(acc[rt][ct][reg]);
          acc[rt][ct][reg] = e; s += e;
        }
      s += __shfl_xor(s, 16); s += __shfl_xor(s, 32);
      cs[ct] = s;
    }
    if (q == 0) {
#pragma unroll
      for (int ct = 0; ct < 4; ct++) rs[wr][64 * wc + 16 * ct + r] = cs[ct];
    }
    __syncthreads();
#pragma unroll
    for (int ct = 0; ct < 4; ct++) {
      int nl = 64 * wc + 16 * ct + r;
      float inv = 1.0f / (rs[0][nl] + rs[1][nl]);
      int n = nt * 128 + nl;
      size_t base = (((size_t)(b * 16 + h)) * 4096 + n) * 128;
#pragma unroll
      for (int rt = 0; rt < 4; rt++) {
        int m0 = 64 * wr + 16 * rt + 4 * q;
        u32x2 pk = pack4(acc[rt][ct][0] * inv, acc[rt][ct][1] * inv,
                         acc[rt][ct][2] * inv, acc[rt][ct][3] * inv);
        *(u32x2*)&QA[base + m0] = pk;
      }
    }
  }
  __syncthreads();   // rs WAR hazard between sections

  // ================= ak part: D[n,m] (A=K rows n, B=agent rows m) =================
  {
    f32x4 acc[4][4];
#pragma unroll
    for (int i = 0; i < 4; i++)
#pragma unroll
      for (int j = 0; j < 4; j++) acc[i][j] = z;
#pragma unroll
    for (int ks = 0; ks < 2; ks++) {
      bf16x8 af[4], bv[4];
#pragma unroll
      for (int rt = 0; rt < 4; rt++) af[rt] = ldg8(Kb + (size_t)(64 * wr + 16 * rt + r) * 64 + ks * 32 + q * 8);
#pragma unroll
      for (int ct = 0; ct < 4; ct++) bv[ct] = ldg8(Ah + (size_t)(64 * wc + 16 * ct + r) * 64 + ks * 32 + q * 8);
#pragma unroll
      for (int rt = 0; rt < 4; rt++)
#pragma unroll
        for (int ct = 0; ct < 4; ct++) MFMA16(acc[rt][ct], af[rt], bv[ct]);
    }
    float cs[4] = {0.f, 0.f, 0.f, 0.f};
#pragma unroll
    for (int rt = 0; rt < 4; rt++) {
      const int4 mkv = *(const int4*)&mask[b * 4096 + nt * 128 + 64 * wr + 16 * rt + 4 * q];
      int mka[4] = {mkv.x, mkv.y, mkv.z, mkv.w};
#pragma unroll
      for (int ct = 0; ct < 4; ct++) {
#pragma unroll
        for (int reg = 0; reg < 4; reg++) {
          float e = mka[reg] ? __expf(acc[rt][ct][reg]) : 0.0f;
          acc[rt][ct][reg] = e; cs[ct] += e;
        }
      }
    }
#pragma unroll
    for (int ct = 0; ct < 4; ct++) {
      float s = cs[ct];
      s += __shfl_xor(s, 16); s += __shfl_xor(s, 32);
      cs[ct] = s;
    }
    if (q == 0) {
#pragma unroll
      for (int ct = 0; ct < 4; ct++) rs[wr][64 * wc + 16 * ct + r] = cs[ct];
    }
#pragma unroll
    for (int ct = 0; ct < 4; ct++) {
      int m = 64 * wc + 16 * ct + r;
      size_t base = (((size_t)(b * 16 + h)) * 128 + m) * 4096;
#pragma unroll
      for (int rt = 0; rt < 4; rt++) {
        int n0 = nt * 128 + 64 * wr + 16 * rt + 4 * q;
        u32x2 pk = pack4(acc[rt][ct][0], acc[rt][ct][1], acc[rt][ct][2], acc[rt][ct][3]);
        *(u32x2*)&E[base + n0] = pk;
      }
    }
    __syncthreads();
    if (tid < 128) atomicAdd(&rowsum[(b * 16 + h) * 128 + tid], rs[0][tid] + rs[1][tid]);
  }
}

// ---- mix: MIX[g,m,n] = sum_h Wak[g,h]*E[h,m,n]/rowsum[h,m]  (4 elems/thread, 8B IO) --
__global__ __launch_bounds__(256) void k_mix(
    const unsigned short* __restrict__ E, const float* __restrict__ rowsum,
    const float* __restrict__ Wak, unsigned short* __restrict__ MIX)
{
  const int tid = threadIdx.x;
  const int m = blockIdx.y, b = blockIdx.z;
  __shared__ float wv[256];
  __shared__ float inv[16];
  wv[tid] = Wak[tid];
  if (tid < 16) inv[tid] = 1.0f / rowsum[(b * 16 + tid) * 128 + m];
  __syncthreads();
  const int n0 = (blockIdx.x * 256 + tid) * 4;
  float p[16][4];
#pragma unroll
  for (int h = 0; h < 16; h++) {
    u32x2 v = *(const u32x2*)&E[(((size_t)(b * 16 + h)) * 128 + m) * 4096 + n0];
    float iv = inv[h];
    p[h][0] = bf2f((unsigned short)(v.x & 0xffff)) * iv;
    p[h][1] = bf2f((unsigned short)(v.x >> 16)) * iv;
    p[h][2] = bf2f((unsigned short)(v.y & 0xffff)) * iv;
    p[h][3] = bf2f((unsigned short)(v.y >> 16)) * iv;
  }
#pragma unroll
  for (int g = 0; g < 16; g++) {
    float s0 = 0.f, s1 = 0.f, s2 = 0.f, s3 = 0.f;
#pragma unroll
    for (int h = 0; h < 16; h++) {
      float wgh = wv[g * 16 + h];
      s0 += wgh * p[h][0]; s1 += wgh * p[h][1]; s2 += wgh * p[h][2]; s3 += wgh * p[h][3];
    }
    *(u32x2*)&MIX[(((size_t)(b * 16 + g)) * 128 + m) * 4096 + n0] = pack4(s0, s1, s2, s3);
  }
}

// ------ k_ao: partial AO_T planes P[kc][b,g,d,m] = MIX[b,g] @ V[b,g] (k-chunk) --------
__global__ __launch_bounds__(256) void k_ao(
    const unsigned short* __restrict__ MIX, const unsigned short* __restrict__ Vt,
    float* __restrict__ P)
{
  const int tid = threadIdx.x, lane = tid & 63, w4 = tid >> 6;
  const int q = lane >> 4, r = lane & 15;
  const int kc = blockIdx.x, g = blockIdx.y, b = blockIdx.z;
  const unsigned short* Abase = MIX + ((size_t)(b * 16 + g)) * 128 * 4096;
  const unsigned short* Bbase = Vt + ((size_t)(b * 16 + g)) * 64 * 4096;
  f32x4 acc[2][4];
  const f32x4 z = {0.f, 0.f, 0.f, 0.f};
#pragma unroll
  for (int i = 0; i < 2; i++)
#pragma unroll
    for (int j = 0; j < 4; j++) acc[i][j] = z;
  for (int n = kc * 512; n < kc * 512 + 512; n += 32) {
    bf16x8 af[2], bv[4];
#pragma unroll
    for (int rt = 0; rt < 2; rt++) af[rt] = ldg8(Abase + (size_t)(32 * w4 + 16 * rt + r) * 4096 + n + q * 8);
#pragma unroll
    for (int ct = 0; ct < 4; ct++) bv[ct] = ldg8(Bbase + (size_t)(16 * ct + r) * 4096 + n + q * 8);
#pragma unroll
    for (int rt = 0; rt < 2; rt++)
#pragma unroll
      for (int ct = 0; ct < 4; ct++) MFMA16(acc[rt][ct], af[rt], bv[ct]);
  }
  float* Pp = P + (size_t)kc * 524288 + ((size_t)(b * 16 + g)) * 8192;
#pragma unroll
  for (int rt = 0; rt < 2; rt++)
#pragma unroll
    for (int ct = 0; ct < 4; ct++) {
      int m0 = 32 * w4 + 16 * rt + 4 * q, d = 16 * ct + r;
      *(f32x4*)&Pp[(size_t)d * 128 + m0] = acc[rt][ct];   // regs = consecutive m
    }
}

// ------ aored: AOt = sum_kc P[kc]  (524288 fp32) --------------------------------------
__global__ __launch_bounds__(256) void k_aored(
    const float* __restrict__ P, float* __restrict__ AOt)
{
  size_t i = ((size_t)blockIdx.x * 256 + threadIdx.x) * 4;
  f32x4 s = *(const f32x4*)&P[i];
#pragma unroll
  for (int kc = 1; kc < 8; kc++) {
    f32x4 v = *(const f32x4*)&P[(size_t)kc * 524288 + i];
    s[0] += v[0]; s[1] += v[1]; s[2] += v[2]; s[3] += v[3];
  }
  *(f32x4*)&AOt[i] = s;
}

// ---- mixqa: QAmix[g,plane] = sum_h Wqa[g,h]*QA[h,plane]  (4 elems/thread, 8B IO) -----
__global__ __launch_bounds__(256) void k_mixqa(
    const unsigned short* __restrict__ QA, const float* __restrict__ Wqa,
    unsigned short* __restrict__ QAmix)
{
  const int tid = threadIdx.x;
  const int b = blockIdx.y;
  __shared__ float wv[256];
  wv[tid] = Wqa[tid];
  __syncthreads();
  const size_t i0 = ((size_t)blockIdx.x * 256 + tid) * 4;   // plane 524288 elems
  float p[16][4];
#pragma unroll
  for (int h = 0; h < 16; h++) {
    u32x2 v = *(const u32x2*)&QA[((size_t)(b * 16 + h)) * 524288 + i0];
    p[h][0] = bf2f((unsigned short)(v.x & 0xffff));
    p[h][1] = bf2f((unsigned short)(v.x >> 16));
    p[h][2] = bf2f((unsigned short)(v.y & 0xffff));
    p[h][3] = bf2f((unsigned short)(v.y >> 16));
  }
#pragma unroll
  for (int g = 0; g < 16; g++) {
    float s0 = 0.f, s1 = 0.f, s2 = 0.f, s3 = 0.f;
#pragma unroll
    for (int h = 0; h < 16; h++) {
      float wgh = wv[g * 16 + h];
      s0 += wgh * p[h][0]; s1 += wgh * p[h][1]; s2 += wgh * p[h][2]; s3 += wgh * p[h][3];
    }
    *(u32x2*)&QAmix[((size_t)(b * 16 + g)) * 524288 + i0] = pack4(s0, s1, s2, s3);
  }
}

// ---- o1: swapped roles -> D[d,n]; out1[b,n,g*64+d] 8B stores; reads AO_T fp32 --------
__global__ __launch_bounds__(256) void k_o1(
    const unsigned short* __restrict__ QAmix, const float* __restrict__ AOt,
    unsigned short* __restrict__ out1)
{
  const int tid = threadIdx.x, lane = tid & 63, w4 = tid >> 6;
  const int q = lane >> 4, r = lane & 15;
  const int nt = blockIdx.x, g = blockIdx.y, b = blockIdx.z;
  const unsigned short* Bbase = QAmix + (((size_t)(b * 16 + g)) * 4096 + nt * 128) * 128;
  const float* Abase = AOt + ((size_t)(b * 16 + g)) * 8192;   // [d][m]
  f32x4 acc[4][2];
  const f32x4 z = {0.f, 0.f, 0.f, 0.f};
#pragma unroll
  for (int i = 0; i < 4; i++)
#pragma unroll
    for (int j = 0; j < 2; j++) acc[i][j] = z;
#pragma unroll
  for (int ks = 0; ks < 4; ks++) {
    bf16x8 af[4], bv[2];
#pragma unroll
    for (int rt = 0; rt < 4; rt++) {
      const float* p = Abase + (size_t)(16 * rt + r) * 128 + ks * 32 + q * 8;
      f32x4 f0 = *(const f32x4*)p;
      f32x4 f1 = *(const f32x4*)(p + 4);
      bf16x8 t;
#pragma unroll
      for (int jj = 0; jj < 4; jj++) { t[jj] = (__bf16)f0[jj]; t[4 + jj] = (__bf16)f1[jj]; }
      af[rt] = t;
    }
#pragma unroll
    for (int ct = 0; ct < 2; ct++)
      bv[ct] = ldg8(Bbase + (size_t)(32 * w4 + 16 * ct + r) * 128 + ks * 32 + q * 8);
#pragma unroll
    for (int rt = 0; rt < 4; rt++)
#pragma unroll
      for (int ct = 0; ct < 2; ct++) MFMA16(acc[rt][ct], af[rt], bv[ct]);
  }
#pragma unroll
  for (int ct = 0; ct < 2; ct++) {
    int n = nt * 128 + 32 * w4 + 16 * ct + r;
    size_t base = ((size_t)b * 4096 + n) * 1024 + g * 64;
#pragma unroll
    for (int rt = 0; rt < 4; rt++) {
      int d0 = 16 * rt + 4 * q;
      u32x2 pk = pack4(acc[rt][ct][0], acc[rt][ct][1], acc[rt][ct][2], acc[rt][ct][3]);
      *(u32x2*)&out1[base + d0] = pk;
    }
  }
}

// ------- fin2: out[16384,1024] = out1 @ WoT^T, mask rows, fp32; 256x256 tiles ---------
__global__ __launch_bounds__(512, 2) void k_fin2(
    const unsigned short* __restrict__ A, const unsigned short* __restrict__ Bt,
    const int* __restrict__ mask, float* __restrict__ out)
{
  __shared__ __align__(16) unsigned short lds[4][16384];
  const int tid = threadIdx.x, lane = tid & 63, w = tid >> 6;
  const int q = lane >> 4, r = lane & 15, wm = w >> 2, wn = w & 3;
  const int row0 = blockIdx.x * 256, col0 = blockIdx.y * 256;

  f32x4 acc[8][4];
  gemm_core_256(A, Bt, row0, col0, 0, lds, acc);

#pragma unroll
  for (int rt = 0; rt < 8; rt++) {
    const int4 mkv = *(const int4*)&mask[row0 + wm * 128 + rt * 16 + 4 * q];
    int mka[4] = {mkv.x, mkv.y, mkv.z, mkv.w};
#pragma unroll
    for (int reg = 0; reg < 4; reg++) {
      int row = row0 + wm * 128 + rt * 16 + 4 * q + reg;
#pragma unroll
      for (int ct = 0; ct < 4; ct++) {
        int c = col0 + wn * 64 + ct * 16 + r;
        out[(size_t)row * 1024 + c] = mka[reg] ? acc[rt][ct][reg] : 0.0f;
      }
    }
  }
}

// =====================================================================================
extern "C" void kernel_launch(void* const* d_in, const int* in_sizes, int n_in,
                              void* d_out, int out_size, void* d_ws, size_t ws_size,
                              hipStream_t stream) {
  const float* x    = (const float*)d_in[0];
  const int*   mask = (const int*)d_in[1];
  const float* Wqkv = (const float*)d_in[2];
  const float* ag   = (const float*)d_in[3];
  const float* Wqa  = (const float*)d_in[4];
  const float* Wak  = (const float*)d_in[5];
  const float* Wout = (const float*)d_in[6];
  float* out = (float*)d_out;
  char* ws = (char*)d_ws;

  // workspace layout, lifetime-overlapped; total 239,370,240 B (unchanged)
  unsigned short* QA    = (unsigned short*)(ws + 0);           // [qk -> mixqa]
  unsigned short* QQ    = (unsigned short*)(ws + 67108864);    // Q [gemm -> qk]
  unsigned short* KK    = (unsigned short*)(ws + 67108864 + 33554432);  // K [gemm -> qk]
  unsigned short* MIX   = QQ;                                  // [mix -> ao] (spans QQ+KK)
  unsigned short* out1  = QQ;                                  // [o1 -> fin2]
  unsigned short* VT    = (unsigned short*)(ws + 134217728);   // Vt [gemm -> ao]
  unsigned short* Xb    = (unsigned short*)(ws + 167772160);   // [prep -> gemm]
  unsigned short* WqkvT = (unsigned short*)(ws + 167772160 + 33554432);
  unsigned short* E     = Xb;                                  // [qk -> mix]
  float*          Ppart = (float*)Xb;                          // 16MB [ao -> aored] (E dead)
  unsigned short* QAmix = Xb;                                  // [mixqa -> o1] (Ppart dead)
  char* sm = ws + 234881024;
  unsigned short* Ab  = (unsigned short*)(sm);                 // 256 KB
  unsigned short* WoT = (unsigned short*)(sm + 262144);        // 2 MB
  float* rowsum = (float*)(sm + 262144 + 2097152);             // 32 KB
  float* AOt    = (float*)(sm + 262144 + 2097152 + 32768);     // 2 MB [b,g,d,m] fp32

  k_prep<<<20616, 256, 0, stream>>>(x, Wqkv, ag, Wout, Xb, WqkvT, Ab, WoT, rowsum);
  k_gemm_qkv<<<dim3(64, 12), 512, 0, stream>>>(Xb, WqkvT, QQ, KK, VT);
  k_qk<<<dim3(32, 16, 4), 256, 0, stream>>>(QQ, KK, Ab, mask, QA, E, rowsum);
  k_mix<<<dim3(4, 128, 4), 256, 0, stream>>>(E, rowsum, Wak, MIX);
  k_ao<<<dim3(8, 16, 4), 256, 0, stream>>>(MIX, VT, Ppart);
  k_aored<<<512, 256, 0, stream>>>(Ppart, AOt);
  k_mixqa<<<dim3(512, 4), 256, 0, stream>>>(QA, Wqa, QAmix);
  k_o1<<<dim3(32, 16, 4), 256, 0, stream>>>(QAmix, AOt, out1);
  k_fin2<<<dim3(64, 4), 512, 0, stream>>>(out1, WoT, mask, out);
}